// Round 13
// baseline (1459.327 us; speedup 1.0000x reference)
//
#include <hip/hip_runtime.h>
#include <hip/hip_bf16.h>
#include <math.h>

typedef __hip_bfloat16 bf16;
typedef __attribute__((ext_vector_type(8))) short bf16x8;
typedef __attribute__((ext_vector_type(4))) float f32x4;
typedef unsigned long long u64;

#define B_SZ 4
#define SEQ  4096
#define DM   256
#define NST  16
#define NCHK 64
#define LC   (SEQ/NCHK)      /* 64 */
#define MT   (B_SZ*SEQ)      /* 16384 rows of (b,l) */
#define CT   4               /* l-tile per conv thread */
#define NSEG (B_SZ*16*NCHK)  /* 4096 scan segments (blocks) */

__device__ __forceinline__ float silu_f(float v){ return v / (1.f + __expf(-v)); }
__device__ __forceinline__ float softplus_f(float v){
  return (v > 15.f) ? v : __logf(1.f + __expf(v));
}
__device__ __forceinline__ short f2bf(float f){
  union { bf16 h; short s; } u; u.h = __float2bfloat16(f); return u.s;
}
__device__ __forceinline__ float bf2f(short s){
  union { unsigned int i; float f; } v;
  v.i = ((unsigned int)(unsigned short)s) << 16; return v.f;
}
__device__ __forceinline__ float4 bf4_to_f4(uint2 q){
  float4 f;
  f.x = bf2f((short)(q.x & 0xffffu)); f.y = bf2f((short)(q.x >> 16));
  f.z = bf2f((short)(q.y & 0xffffu)); f.w = bf2f((short)(q.y >> 16));
  return f;
}
__device__ __forceinline__ short4 f4_to_bf4(float4 f){
  short4 s; s.x = f2bf(f.x); s.y = f2bf(f.y); s.z = f2bf(f.z); s.w = f2bf(f.w);
  return s;
}
__device__ __forceinline__ u64 pack2f(float a, float b){
  union { float f[2]; u64 u; } v; v.f[0] = a; v.f[1] = b; return v.u;
}
__device__ __forceinline__ float2 unpack2f(u64 u){
  union { u64 u; float f[2]; } v; v.u = u; return make_float2(v.f[0], v.f[1]);
}

// DPP row_shr:N add step; after N=8,4,2,1 lane 15 of each row = row sum.
template<int CTRL>
__device__ __forceinline__ float dpp_add_step(float v){
  int x = __builtin_amdgcn_update_dpp(0, __float_as_int(v), CTRL, 0xf, 0xf, true);
  return v + __int_as_float(x);
}

// ---------------------------------------------------------------------------
// Weight pre-conversion: w_in (768x256) and w_o1 (256x256) fp32 -> bf16.
// ---------------------------------------------------------------------------
__global__ __launch_bounds__(256)
void cvt_w_k(const float* __restrict__ w_in, const float* __restrict__ w_o1,
             short* __restrict__ w_in_b, short* __restrict__ w_o1_b)
{
  int i = blockIdx.x * 256 + threadIdx.x;     // 0..65535
  if (i < 49152) {
    float4 q = *(const float4*)&w_in[i * 4];
    *(short4*)&w_in_b[i * 4] = f4_to_bf4(q);
  } else {
    int j = i - 49152;                        // 0..16383
    float4 q = *(const float4*)&w_o1[j * 4];
    *(short4*)&w_o1_b[j * 4] = f4_to_bf4(q);
  }
}

// ---------------------------------------------------------------------------
// MFMA bf16 GEMM. Grid (m-tiles, n-tiles): m on blockIdx.x (XCD L2 reuse).
// A: fp32 (ABF=0) or bf16 (ABF=1, pure 16B copy). Bw bf16 (pre-converted).
// EPI 0: plain store. EPI 2: (acc * zc[m,n] * cwx[n] + bias[n]) (zc bf16).
// ---------------------------------------------------------------------------
template<int EPI, bool ABF, bool OBF>
__global__ __launch_bounds__(256)
void mfma_gemm_k(const void* __restrict__ Av, const short* __restrict__ Bw,
                 void* __restrict__ Outv, int N, int K,
                 const float* __restrict__ bias, const short* __restrict__ zc,
                 const float* __restrict__ cwx)
{
  constexpr int BM = 128, BN = 128, BK = 32, LDP = 40;  // pad 32->40 shorts
  __shared__ short As[BM * LDP];
  __shared__ short Bs[BN * LDP];
  const int tid  = threadIdx.x;
  const int wave = tid >> 6, lane = tid & 63;
  const int quad = lane >> 4, l16 = lane & 15;
  const int wm = (wave & 1) * 64, wn = (wave >> 1) * 64;
  const int m0 = blockIdx.x * BM, n0 = blockIdx.y * BN;
  const int srow = tid >> 3;            // fp32-A path
  const int skq  = (tid & 7) * 4;
  const int crow = tid >> 2;            // bf16 copy path
  const int cck  = (tid & 3) * 8;

  f32x4 acc[4][4] = {};

  for (int k0 = 0; k0 < K; k0 += BK) {
    if constexpr (ABF) {
      #pragma unroll
      for (int p = 0; p < 2; p++) {
        int row = p * 64 + crow;
        uint4 v = *(const uint4*)((const short*)Av + (size_t)(m0 + row) * K + k0 + cck);
        *(uint4*)&As[row * LDP + cck] = v;
      }
    } else {
      #pragma unroll
      for (int p = 0; p < 4; p++) {
        int row = p * 32 + srow;
        size_t ga = (size_t)(m0 + row) * K + k0 + skq;
        float4 q = *(const float4*)((const float*)Av + ga);
        *(short4*)&As[row * LDP + skq] = f4_to_bf4(q);
      }
    }
    {
      #pragma unroll
      for (int p = 0; p < 2; p++) {
        int row = p * 64 + crow;
        uint4 v = *(const uint4*)(Bw + (size_t)(n0 + row) * K + k0 + cck);
        *(uint4*)&Bs[row * LDP + cck] = v;
      }
    }
    __syncthreads();
    bf16x8 fa[4], fb[4];
    #pragma unroll
    for (int i = 0; i < 4; i++) {
      fa[i] = *(const bf16x8*)&As[(wm + i * 16 + l16) * LDP + quad * 8];
      fb[i] = *(const bf16x8*)&Bs[(wn + i * 16 + l16) * LDP + quad * 8];
    }
    #pragma unroll
    for (int i = 0; i < 4; i++)
      #pragma unroll
      for (int j = 0; j < 4; j++)
        acc[i][j] = __builtin_amdgcn_mfma_f32_16x16x32_bf16(fa[i], fb[j], acc[i][j], 0, 0, 0);
    __syncthreads();
  }

  #pragma unroll
  for (int i = 0; i < 4; i++) {
    #pragma unroll
    for (int j = 0; j < 4; j++) {
      int n = n0 + wn + j * 16 + l16;
      #pragma unroll
      for (int r = 0; r < 4; r++) {
        int m = m0 + wm + i * 16 + quad * 4 + r;
        float v = acc[i][j][r];
        if constexpr (EPI == 2)
          v = v * bf2f(zc[(size_t)m * N + n]) * cwx[n] + bias[n];
        if constexpr (OBF) ((short*)Outv)[(size_t)m * N + n] = f2bf(v);
        else               ((float*)Outv)[(size_t)m * N + n] = v;
      }
    }
  }
}

// ---------------------------------------------------------------------------
// Fused K3+K4 (TM=32): xdbl = xc @ x_proj_w^T; dtv = softplus(dt_r@wdt^T+2b).
// ---------------------------------------------------------------------------
__global__ __launch_bounds__(256)
void gemm34_k(const short* __restrict__ xcb,
              const float* __restrict__ Bw,
              const float* __restrict__ wdt,
              const float* __restrict__ bdt,
              float* __restrict__ xdbl,
              float* __restrict__ dtv)
{
  constexpr int TM = 32, TK = 16, NN = 48;
  __shared__ __align__(16) float As[TK][TM + 4];
  __shared__ __align__(16) float Bs[TK][64 + 4];
  __shared__ __align__(16) float dt_s[TM][20];
  __shared__ __align__(16) float wdt_s[256][20];
  const int tid = threadIdx.x;
  const int tn = tid & 15, tm = tid >> 4;
  const int m0 = blockIdx.x * TM;
  float acc[2][4] = {};
  const int mlA = tid >> 3, kdA = (tid & 7) * 2;
  const int mlB = tid >> 2, kqB = (tid & 3) * 4;

  {
    float4 q0 = *(const float4*)&wdt[tid * 16 + 0];
    float4 q1 = *(const float4*)&wdt[tid * 16 + 4];
    float4 q2 = *(const float4*)&wdt[tid * 16 + 8];
    float4 q3 = *(const float4*)&wdt[tid * 16 + 12];
    *(float4*)&wdt_s[tid][0]  = q0;
    *(float4*)&wdt_s[tid][4]  = q1;
    *(float4*)&wdt_s[tid][8]  = q2;
    *(float4*)&wdt_s[tid][12] = q3;
  }

  for (int k0 = 0; k0 < 256; k0 += TK) {
    {
      size_t off = (size_t)(m0 + mlA) * 256 + k0 + kdA;
      unsigned int v = *(const unsigned int*)(xcb + off);
      As[kdA + 0][mlA] = bf2f((short)(v & 0xffffu));
      As[kdA + 1][mlA] = bf2f((short)(v >> 16));
    }
    {
      float v0 = 0.f, v1 = 0.f, v2 = 0.f, v3 = 0.f;
      if (mlB < NN) {
        float4 q = *(const float4*)(Bw + (size_t)mlB * 256 + k0 + kqB);
        v0 = q.x; v1 = q.y; v2 = q.z; v3 = q.w;
      }
      Bs[kqB+0][mlB] = v0; Bs[kqB+1][mlB] = v1; Bs[kqB+2][mlB] = v2; Bs[kqB+3][mlB] = v3;
    }
    __syncthreads();
    #pragma unroll
    for (int k = 0; k < TK; k++) {
      float2 av = *(const float2*)&As[k][tm << 1];
      float4 bv = *(const float4*)&Bs[k][tn << 2];
      float a[2] = {av.x, av.y};
      float b[4] = {bv.x, bv.y, bv.z, bv.w};
      #pragma unroll
      for (int i = 0; i < 2; i++)
        #pragma unroll
        for (int j = 0; j < 4; j++)
          acc[i][j] = fmaf(a[i], b[j], acc[i][j]);
    }
    __syncthreads();
  }

  #pragma unroll
  for (int i = 0; i < 2; i++) {
    int m = m0 + (tm << 1) + i;
    #pragma unroll
    for (int j = 0; j < 4; j++) {
      int n = (tn << 2) + j;
      float v = acc[i][j];
      if (n < NN) xdbl[(size_t)m * NN + n] = v;
      if (tn < 4) dt_s[(tm << 1) + i][n] = v;
    }
  }
  __syncthreads();

  const int c0 = tid & 63, rg = tid >> 6;
  float w[4][16];
  float bb[4];
  #pragma unroll
  for (int cc = 0; cc < 4; cc++) {
    int col = cc * 64 + c0;
    #pragma unroll
    for (int q = 0; q < 4; q++) {
      float4 t = *(const float4*)&wdt_s[col][q * 4];
      w[cc][q*4+0] = t.x; w[cc][q*4+1] = t.y; w[cc][q*4+2] = t.z; w[cc][q*4+3] = t.w;
    }
    bb[cc] = 2.f * bdt[col];
  }
  #pragma unroll
  for (int rr = 0; rr < 8; rr++) {
    int row = rg * 8 + rr;
    float dr[16];
    #pragma unroll
    for (int q = 0; q < 4; q++) {
      float4 t = *(const float4*)&dt_s[row][q * 4];
      dr[q*4+0] = t.x; dr[q*4+1] = t.y; dr[q*4+2] = t.z; dr[q*4+3] = t.w;
    }
    #pragma unroll
    for (int cc = 0; cc < 4; cc++) {
      float s = bb[cc];
      #pragma unroll
      for (int k = 0; k < 16; k++) s = fmaf(dr[k], w[cc][k], s);
      dtv[(size_t)(m0 + row) * 256 + cc * 64 + c0] = softplus_f(s);
    }
  }
}

// ---------------------------------------------------------------------------
// Depthwise conv + SiLU, register-sliding-window, bf16 in / bf16 out.
// ---------------------------------------------------------------------------
__global__ __launch_bounds__(256)
void conv_silu_k(const short* __restrict__ xyzb,
                 const float* __restrict__ wx, const float* __restrict__ bx,
                 const float* __restrict__ wy, const float* __restrict__ by,
                 const float* __restrict__ wz, const float* __restrict__ bz,
                 short* __restrict__ xcb, short* __restrict__ ycb,
                 short* __restrict__ zcb)
{
  int idx = blockIdx.x * 256 + threadIdx.x;
  int c4 = idx % 192;
  int lt = idx / 192;
  int row0 = lt * CT;
  int l0 = row0 & (SEQ - 1);

  float4 win[CT + 4];
  #pragma unroll
  for (int i = 0; i < CT + 4; i++) {
    int l = l0 + i - 2;
    if (l >= 0 && l < SEQ)
      win[i] = bf4_to_f4(*(const uint2*)(xyzb + (size_t)(row0 + i - 2) * 768 + c4 * 4));
    else
      win[i] = make_float4(0.f, 0.f, 0.f, 0.f);
  }

  if (c4 < 64) {
    int d = c4 * 4;
    float4 w  = *(const float4*)&wx[d];
    float4 bb = *(const float4*)&bx[d];
    #pragma unroll
    for (int t = 0; t < CT; t++) {
      float4 v = win[t + 2], o;
      o.x = silu_f(fmaf(v.x, w.x, bb.x));
      o.y = silu_f(fmaf(v.y, w.y, bb.y));
      o.z = silu_f(fmaf(v.z, w.z, bb.z));
      o.w = silu_f(fmaf(v.w, w.w, bb.w));
      *(short4*)&xcb[(size_t)(row0 + t) * 256 + d] = f4_to_bf4(o);
    }
  } else if (c4 < 128) {
    int d = (c4 - 64) * 4;
    float wq[4][3];
    #pragma unroll
    for (int q = 0; q < 4; q++)
      #pragma unroll
      for (int j = 0; j < 3; j++) wq[q][j] = wy[(d + q) * 3 + j];
    float4 bb = *(const float4*)&by[d];
    #pragma unroll
    for (int t = 0; t < CT; t++) {
      float a0 = bb.x, a1 = bb.y, a2 = bb.z, a3 = bb.w;
      #pragma unroll
      for (int j = 0; j < 3; j++) {
        float4 v = win[t + 1 + j];
        a0 = fmaf(v.x, wq[0][j], a0);
        a1 = fmaf(v.y, wq[1][j], a1);
        a2 = fmaf(v.z, wq[2][j], a2);
        a3 = fmaf(v.w, wq[3][j], a3);
      }
      float4 o; o.x = silu_f(a0); o.y = silu_f(a1); o.z = silu_f(a2); o.w = silu_f(a3);
      *(short4*)&ycb[(size_t)(row0 + t) * 256 + d] = f4_to_bf4(o);
    }
  } else {
    int d = (c4 - 128) * 4;
    float wq[4][5];
    #pragma unroll
    for (int q = 0; q < 4; q++)
      #pragma unroll
      for (int j = 0; j < 5; j++) wq[q][j] = wz[(d + q) * 5 + j];
    float4 bb = *(const float4*)&bz[d];
    #pragma unroll
    for (int t = 0; t < CT; t++) {
      float a0 = bb.x, a1 = bb.y, a2 = bb.z, a3 = bb.w;
      #pragma unroll
      for (int j = 0; j < 5; j++) {
        float4 v = win[t + j];
        a0 = fmaf(v.x, wq[0][j], a0);
        a1 = fmaf(v.y, wq[1][j], a1);
        a2 = fmaf(v.z, wq[2][j], a2);
        a3 = fmaf(v.w, wq[3][j], a3);
      }
      float4 o; o.x = silu_f(a0); o.y = silu_f(a1); o.z = silu_f(a2); o.w = silu_f(a3);
      *(short4*)&zcb[(size_t)(row0 + t) * 256 + d] = f4_to_bf4(o);
    }
  }
}

// ---------------------------------------------------------------------------
// Single-pass chunked selective scan with decoupled look-back.
// Block = (chunk, dgroup, b); 256 thr = 256 (d,n) chains. Stage once;
// phase 1: local (P,h); publish partial (agent atomics, flag=1);
// look-back: fold predecessor partials, short-circuit at inclusive (flag=2);
// publish inclusive; phase 2: emit y from true H0, DPP reduce, fused *yc.
// flags[] must be zeroed before launch (hipMemsetAsync in-stream).
// ---------------------------------------------------------------------------
__global__ __launch_bounds__(256)
void scan_fused_k(const short* __restrict__ xcb,    // u (bf16), (MT,256)
                  const float* __restrict__ dtv,    // delta, (MT,256)
                  const float* __restrict__ xdbl,   // (MT,48): [dt_r | B | C]
                  const float* __restrict__ A_log,
                  const float* __restrict__ Dp,
                  const short* __restrict__ ycb,    // y-gate (bf16)
                  short* __restrict__ poutb,        // out (bf16): p*yc
                  u64* __restrict__ partial,        // [NSEG][256] {P,h}
                  float* __restrict__ incl,         // [NSEG][256] h
                  int* __restrict__ flags)          // [NSEG] 0/1/2
{
  __shared__ __align__(16) float2 du2_s[16 * 66];   // [ch][t] {delta, delta*u}
  __shared__ __align__(16) float2 BC_s [16 * 66];   // [n][t]  {B, C}
  __shared__ __align__(16) float  y_s  [16 * 68];   // [ch][t]
  const int tid = threadIdx.x;
  const int n = tid & 15, dl = tid >> 4;
  const int ch = blockIdx.x;
  const int dg = blockIdx.y;
  const int b  = blockIdx.z;
  const int d0 = dg * 16;
  const int d  = d0 + dl;
  const int t0 = ch * LC;
  const size_t brow = (size_t)b * SEQ;
  const int sbase = (b * 16 + dg) * NCHK;
  const int e = sbase + ch;

  float u_r[4];
  #pragma unroll
  for (int i = 0; i < 4; i++) {               // cooperative coalesced staging
    int t = (tid >> 4) + i * 16;
    int dd = tid & 15;
    size_t row = brow + t0 + t;
    float uval = bf2f(xcb[row * 256 + d0 + dd]);
    float dval = dtv[row * 256 + d0 + dd];
    du2_s[dd * 66 + t] = make_float2(dval, dval * uval);
    BC_s[dd * 66 + t] = make_float2(xdbl[row * 48 + 16 + dd],
                                    xdbl[row * 48 + 32 + dd]);
    u_r[i] = uval;
  }
  __syncthreads();

  const float A_dn = -__expf(A_log[d * NST + n]);

  // ---- phase 1: local scan (h from 0, decay product P) ----
  float h = 0.f, P = 1.f;
  for (int t4 = 0; t4 < LC; t4 += 4) {
    float4 a = *(const float4*)&du2_s[dl * 66 + t4];
    float4 c = *(const float4*)&du2_s[dl * 66 + t4 + 2];
    float4 e4 = *(const float4*)&BC_s[n * 66 + t4];
    float4 g4 = *(const float4*)&BC_s[n * 66 + t4 + 2];
    float dA[4] = {__expf(a.x * A_dn), __expf(a.z * A_dn),
                   __expf(c.x * A_dn), __expf(c.z * A_dn)};
    float du[4] = {a.y, a.w, c.y, c.w};
    float Bv[4] = {e4.x, e4.z, g4.x, g4.z};
    #pragma unroll
    for (int j = 0; j < 4; j++) {
      h = fmaf(dA[j], h, du[j] * Bv[j]);
      P *= dA[j];
    }
  }

  // ---- publish partial ----
  __hip_atomic_store(&partial[(size_t)e * 256 + tid], pack2f(P, h),
                     __ATOMIC_RELAXED, __HIP_MEMORY_SCOPE_AGENT);
  __syncthreads();                            // drains vmcnt for all threads
  if (tid == 0)
    __hip_atomic_store(&flags[e], 1, __ATOMIC_RELEASE, __HIP_MEMORY_SCOPE_AGENT);

  // ---- look-back: fold predecessors (newest -> oldest) ----
  float H0 = 0.f;
  if (ch > 0) {
    float accP = 1.f, acch = 0.f;
    int p = ch - 1;
    while (true) {
      int st = __hip_atomic_load(&flags[sbase + p], __ATOMIC_ACQUIRE,
                                 __HIP_MEMORY_SCOPE_AGENT);
      if (st == 0) { __builtin_amdgcn_s_sleep(2); continue; }
      if (st == 2) {
        float hp = __hip_atomic_load(&incl[(size_t)(sbase + p) * 256 + tid],
                                     __ATOMIC_RELAXED, __HIP_MEMORY_SCOPE_AGENT);
        H0 = fmaf(accP, hp, acch);
        break;
      }
      float2 ph = unpack2f(__hip_atomic_load(&partial[(size_t)(sbase + p) * 256 + tid],
                                             __ATOMIC_RELAXED, __HIP_MEMORY_SCOPE_AGENT));
      acch = fmaf(accP, ph.y, acch);
      accP *= ph.x;
      if (p == 0) { H0 = acch; break; }     // chunk 0's partial is inclusive
      --p;
    }
  }

  // ---- publish inclusive ----
  __hip_atomic_store(&incl[(size_t)e * 256 + tid], fmaf(P, H0, h),
                     __ATOMIC_RELAXED, __HIP_MEMORY_SCOPE_AGENT);
  __syncthreads();
  if (tid == 0)
    __hip_atomic_store(&flags[e], 2, __ATOMIC_RELEASE, __HIP_MEMORY_SCOPE_AGENT);

  // ---- phase 2: emit y from true H0 ----
  h = H0;
  for (int t4 = 0; t4 < LC; t4 += 4) {
    float4 a = *(const float4*)&du2_s[dl * 66 + t4];
    float4 c = *(const float4*)&du2_s[dl * 66 + t4 + 2];
    float4 e4 = *(const float4*)&BC_s[n * 66 + t4];
    float4 g4 = *(const float4*)&BC_s[n * 66 + t4 + 2];
    float dA[4] = {__expf(a.x * A_dn), __expf(a.z * A_dn),
                   __expf(c.x * A_dn), __expf(c.z * A_dn)};
    float du[4] = {a.y, a.w, c.y, c.w};
    float Bv[4] = {e4.x, e4.z, g4.x, g4.z};
    float Cv[4] = {e4.y, e4.w, g4.y, g4.w};
    float yv[4];
    #pragma unroll
    for (int j = 0; j < 4; j++) {
      h = fmaf(dA[j], h, du[j] * Bv[j]);
      yv[j] = h * Cv[j];
    }
    #pragma unroll
    for (int j = 0; j < 4; j++) yv[j] = dpp_add_step<0x118>(yv[j]); // shr8
    #pragma unroll
    for (int j = 0; j < 4; j++) yv[j] = dpp_add_step<0x114>(yv[j]); // shr4
    #pragma unroll
    for (int j = 0; j < 4; j++) yv[j] = dpp_add_step<0x112>(yv[j]); // shr2
    #pragma unroll
    for (int j = 0; j < 4; j++) yv[j] = dpp_add_step<0x111>(yv[j]); // shr1
    if (n == 15)
      *(float4*)&y_s[dl * 68 + t4] = make_float4(yv[0], yv[1], yv[2], yv[3]);
  }
  __syncthreads();

  const float Dval = Dp[d0 + n];
  #pragma unroll
  for (int i = 0; i < 4; i++) {               // coalesced writeback, fused *yc
    int t = (tid >> 4) + i * 16;
    size_t row = brow + t0 + t;
    float p = fmaf(Dval, u_r[i], y_s[n * 68 + t]);
    float yg = bf2f(ycb[row * 256 + d0 + n]);
    poutb[row * 256 + d0 + n] = f2bf(p * yg);
  }
}

// ---------------------------------------------------------------------------
extern "C" void kernel_launch(void* const* d_in, const int* in_sizes, int n_in,
                              void* d_out, int out_size, void* d_ws, size_t ws_size,
                              hipStream_t stream)
{
  const float* hs    = (const float*)d_in[0];
  const float* w_in  = (const float*)d_in[1];
  const float* w_xp  = (const float*)d_in[2];
  const float* w_dt  = (const float*)d_in[3];
  const float* b_dt  = (const float*)d_in[4];
  const float* A_log = (const float*)d_in[5];
  const float* Dp    = (const float*)d_in[6];
  const float* w_o1  = (const float*)d_in[7];
  const float* cwx   = (const float*)d_in[8];
  const float* cbx   = (const float*)d_in[9];
  const float* cwy   = (const float*)d_in[10];
  const float* cby   = (const float*)d_in[11];
  const float* cwz   = (const float*)d_in[12];
  const float* cbz   = (const float*)d_in[13];

  char* wsb = (char*)d_ws;
  short* xyzb = (short*)wsb;                            // MT*768 bf16
  short* xcb  = (short*)(wsb + (size_t)MT * 768 * 2);   // MT*256 bf16
  short* ycb  = xcb + (size_t)MT * 256;
  short* zcb  = ycb + (size_t)MT * 256;
  short* pbufb= zcb + (size_t)MT * 256;                 // p*yc (bf16)
  short* w_in_b = pbufb + (size_t)MT * 256;             // 768*256 bf16
  short* w_o1_b = w_in_b + 768 * 256;                   // 256*256 bf16
  float* xdbl = (float*)(w_o1_b + 256 * 256 + 128);     // MT*48 fp32
  float* dtv  = xdbl + (size_t)MT * 48;                 // MT*256 fp32
  u64*   part = (u64*)(dtv + (size_t)MT * 256);         // NSEG*256 u64 (8 MB)
  float* incl = (float*)(part + (size_t)NSEG * 256);    // NSEG*256 f32 (4 MB)
  int*   flags= (int*)(incl + (size_t)NSEG * 256);      // NSEG ints (16 KB)

  dim3 blk(256);

  // K0: weights -> bf16
  cvt_w_k<<<dim3(256), blk, 0, stream>>>(w_in, w_o1, w_in_b, w_o1_b);

  // zero look-back flags (graph-capturable async memset)
  hipMemsetAsync(flags, 0, NSEG * sizeof(int), stream);

  // K1: xyz = hs @ in_proj_w^T  (bf16 MFMA, bf16 out; m-major grid)
  mfma_gemm_k<0, false, true><<<dim3(MT / 128, 768 / 128), blk, 0, stream>>>(
      hs, w_in_b, xyzb, 768, 256, nullptr, nullptr, nullptr);

  // K2: depthwise conv + SiLU -> xcb, ycb, zcb (bf16)
  conv_silu_k<<<dim3((MT / CT) * 192 / 256), blk, 0, stream>>>(
      xyzb, cwx, cbx, cwy, cby, cwz, cbz, xcb, ycb, zcb);

  // K3+K4 fused
  gemm34_k<<<dim3(MT / 32), blk, 0, stream>>>(
      xcb, w_xp, w_dt, b_dt, xdbl, dtv);

  // K5: single-pass scan (decoupled look-back) -> pbufb = (scan out)*yc
  scan_fused_k<<<dim3(NCHK, DM / 16, B_SZ), blk, 0, stream>>>(
      xcb, dtv, xdbl, A_log, Dp, ycb, pbufb, part, incl, flags);

  // K8: out = (pbufb @ out_proj1_w^T) * zc * cwx + cbx  (fp32 out)
  mfma_gemm_k<2, true, false><<<dim3(MT / 128, 256 / 128), blk, 0, stream>>>(
      pbufb, w_o1_b, d_out, 256, 256, cbx, zcb, cwx);
}

// Round 14
// 210.235 us; speedup vs baseline: 6.9414x; 6.9414x over previous
//
#include <hip/hip_runtime.h>
#include <hip/hip_bf16.h>
#include <math.h>

typedef __hip_bfloat16 bf16;
typedef __attribute__((ext_vector_type(8))) short bf16x8;
typedef __attribute__((ext_vector_type(4))) float f32x4;

#define B_SZ 4
#define SEQ  4096
#define DM   256
#define NST  16
#define NCHK 64
#define LC   (SEQ/NCHK)      /* 64 */
#define MT   (B_SZ*SEQ)      /* 16384 rows of (b,l) */
#define CT   8               /* l-tile per conv thread */

__device__ __forceinline__ float silu_f(float v){ return v / (1.f + __expf(-v)); }
__device__ __forceinline__ float softplus_f(float v){
  return (v > 15.f) ? v : __logf(1.f + __expf(v));
}
__device__ __forceinline__ short f2bf(float f){
  union { bf16 h; short s; } u; u.h = __float2bfloat16(f); return u.s;
}
__device__ __forceinline__ float bf2f(short s){
  union { unsigned int i; float f; } v;
  v.i = ((unsigned int)(unsigned short)s) << 16; return v.f;
}
__device__ __forceinline__ float4 bf4_to_f4(uint2 q){
  float4 f;
  f.x = bf2f((short)(q.x & 0xffffu)); f.y = bf2f((short)(q.x >> 16));
  f.z = bf2f((short)(q.y & 0xffffu)); f.w = bf2f((short)(q.y >> 16));
  return f;
}
__device__ __forceinline__ short4 f4_to_bf4(float4 f){
  short4 s; s.x = f2bf(f.x); s.y = f2bf(f.y); s.z = f2bf(f.z); s.w = f2bf(f.w);
  return s;
}

// DPP row_shr:N add step; after N=8,4,2,1 lane 15 of each row = row sum.
template<int CTRL>
__device__ __forceinline__ float dpp_add_step(float v){
  int x = __builtin_amdgcn_update_dpp(0, __float_as_int(v), CTRL, 0xf, 0xf, true);
  return v + __int_as_float(x);
}

// ---------------------------------------------------------------------------
// Input pre-conversion to bf16: w_in (768x256), w_o1 (256x256), hs (MT x 256).
// One float4 per thread; all branch boundaries are multiples of 64.
// ---------------------------------------------------------------------------
__global__ __launch_bounds__(256)
void cvt_in_k(const float* __restrict__ w_in, const float* __restrict__ w_o1,
              const float* __restrict__ hs,
              short* __restrict__ w_in_b, short* __restrict__ w_o1_b,
              short* __restrict__ hsb)
{
  int i = blockIdx.x * 256 + threadIdx.x;     // 0..1114111
  if (i < 49152) {
    float4 q = *(const float4*)&w_in[i * 4];
    *(short4*)&w_in_b[i * 4] = f4_to_bf4(q);
  } else if (i < 65536) {
    int j = i - 49152;
    float4 q = *(const float4*)&w_o1[j * 4];
    *(short4*)&w_o1_b[j * 4] = f4_to_bf4(q);
  } else {
    int j = i - 65536;                        // 0..1048575
    float4 q = *(const float4*)&hs[(size_t)j * 4];
    *(short4*)&hsb[(size_t)j * 4] = f4_to_bf4(q);
  }
}

// ---------------------------------------------------------------------------
// MFMA bf16 GEMM. Grid (m-tiles, n-tiles): m on blockIdx.x (XCD L2 reuse).
// A and Bw both bf16 (pre-converted) -> staging is a pure 16B copy.
// EPI 0: plain store. EPI 2: (acc * zc[m,n] * cwx[n] + bias[n]) (zc bf16).
// ---------------------------------------------------------------------------
template<int EPI, bool OBF>
__global__ __launch_bounds__(256)
void mfma_gemm_k(const short* __restrict__ Av, const short* __restrict__ Bw,
                 void* __restrict__ Outv, int N, int K,
                 const float* __restrict__ bias, const short* __restrict__ zc,
                 const float* __restrict__ cwx)
{
  constexpr int BM = 128, BN = 128, BK = 32, LDP = 40;  // pad 32->40 shorts
  __shared__ short As[BM * LDP];
  __shared__ short Bs[BN * LDP];
  const int tid  = threadIdx.x;
  const int wave = tid >> 6, lane = tid & 63;
  const int quad = lane >> 4, l16 = lane & 15;
  const int wm = (wave & 1) * 64, wn = (wave >> 1) * 64;
  const int m0 = blockIdx.x * BM, n0 = blockIdx.y * BN;
  const int crow = tid >> 2;            // 0..63
  const int cck  = (tid & 3) * 8;       // 0,8,16,24

  f32x4 acc[4][4] = {};

  for (int k0 = 0; k0 < K; k0 += BK) {
    #pragma unroll
    for (int p = 0; p < 2; p++) {
      int row = p * 64 + crow;
      uint4 va = *(const uint4*)(Av + (size_t)(m0 + row) * K + k0 + cck);
      *(uint4*)&As[row * LDP + cck] = va;
      uint4 vb = *(const uint4*)(Bw + (size_t)(n0 + row) * K + k0 + cck);
      *(uint4*)&Bs[row * LDP + cck] = vb;
    }
    __syncthreads();
    bf16x8 fa[4], fb[4];
    #pragma unroll
    for (int i = 0; i < 4; i++) {
      fa[i] = *(const bf16x8*)&As[(wm + i * 16 + l16) * LDP + quad * 8];
      fb[i] = *(const bf16x8*)&Bs[(wn + i * 16 + l16) * LDP + quad * 8];
    }
    #pragma unroll
    for (int i = 0; i < 4; i++)
      #pragma unroll
      for (int j = 0; j < 4; j++)
        acc[i][j] = __builtin_amdgcn_mfma_f32_16x16x32_bf16(fa[i], fb[j], acc[i][j], 0, 0, 0);
    __syncthreads();
  }

  #pragma unroll
  for (int i = 0; i < 4; i++) {
    #pragma unroll
    for (int j = 0; j < 4; j++) {
      int n = n0 + wn + j * 16 + l16;
      #pragma unroll
      for (int r = 0; r < 4; r++) {
        int m = m0 + wm + i * 16 + quad * 4 + r;
        float v = acc[i][j][r];
        if constexpr (EPI == 2)
          v = v * bf2f(zc[(size_t)m * N + n]) * cwx[n] + bias[n];
        if constexpr (OBF) ((short*)Outv)[(size_t)m * N + n] = f2bf(v);
        else               ((float*)Outv)[(size_t)m * N + n] = v;
      }
    }
  }
}

// ---------------------------------------------------------------------------
// Fused K3+K4 (TM=32): xdbl = xc @ x_proj_w^T; dtv = softplus(dt_r@wdt^T+2b).
// ---------------------------------------------------------------------------
__global__ __launch_bounds__(256)
void gemm34_k(const short* __restrict__ xcb,
              const float* __restrict__ Bw,
              const float* __restrict__ wdt,
              const float* __restrict__ bdt,
              float* __restrict__ xdbl,
              float* __restrict__ dtv)
{
  constexpr int TM = 32, TK = 16, NN = 48;
  __shared__ __align__(16) float As[TK][TM + 4];
  __shared__ __align__(16) float Bs[TK][64 + 4];
  __shared__ __align__(16) float dt_s[TM][20];
  __shared__ __align__(16) float wdt_s[256][20];
  const int tid = threadIdx.x;
  const int tn = tid & 15, tm = tid >> 4;
  const int m0 = blockIdx.x * TM;
  float acc[2][4] = {};
  const int mlA = tid >> 3, kdA = (tid & 7) * 2;
  const int mlB = tid >> 2, kqB = (tid & 3) * 4;

  {
    float4 q0 = *(const float4*)&wdt[tid * 16 + 0];
    float4 q1 = *(const float4*)&wdt[tid * 16 + 4];
    float4 q2 = *(const float4*)&wdt[tid * 16 + 8];
    float4 q3 = *(const float4*)&wdt[tid * 16 + 12];
    *(float4*)&wdt_s[tid][0]  = q0;
    *(float4*)&wdt_s[tid][4]  = q1;
    *(float4*)&wdt_s[tid][8]  = q2;
    *(float4*)&wdt_s[tid][12] = q3;
  }

  for (int k0 = 0; k0 < 256; k0 += TK) {
    {
      size_t off = (size_t)(m0 + mlA) * 256 + k0 + kdA;
      unsigned int v = *(const unsigned int*)(xcb + off);
      As[kdA + 0][mlA] = bf2f((short)(v & 0xffffu));
      As[kdA + 1][mlA] = bf2f((short)(v >> 16));
    }
    {
      float v0 = 0.f, v1 = 0.f, v2 = 0.f, v3 = 0.f;
      if (mlB < NN) {
        float4 q = *(const float4*)(Bw + (size_t)mlB * 256 + k0 + kqB);
        v0 = q.x; v1 = q.y; v2 = q.z; v3 = q.w;
      }
      Bs[kqB+0][mlB] = v0; Bs[kqB+1][mlB] = v1; Bs[kqB+2][mlB] = v2; Bs[kqB+3][mlB] = v3;
    }
    __syncthreads();
    #pragma unroll
    for (int k = 0; k < TK; k++) {
      float2 av = *(const float2*)&As[k][tm << 1];
      float4 bv = *(const float4*)&Bs[k][tn << 2];
      float a[2] = {av.x, av.y};
      float b[4] = {bv.x, bv.y, bv.z, bv.w};
      #pragma unroll
      for (int i = 0; i < 2; i++)
        #pragma unroll
        for (int j = 0; j < 4; j++)
          acc[i][j] = fmaf(a[i], b[j], acc[i][j]);
    }
    __syncthreads();
  }

  #pragma unroll
  for (int i = 0; i < 2; i++) {
    int m = m0 + (tm << 1) + i;
    #pragma unroll
    for (int j = 0; j < 4; j++) {
      int n = (tn << 2) + j;
      float v = acc[i][j];
      if (n < NN) xdbl[(size_t)m * NN + n] = v;
      if (tn < 4) dt_s[(tm << 1) + i][n] = v;
    }
  }
  __syncthreads();

  const int c0 = tid & 63, rg = tid >> 6;
  float w[4][16];
  float bb[4];
  #pragma unroll
  for (int cc = 0; cc < 4; cc++) {
    int col = cc * 64 + c0;
    #pragma unroll
    for (int q = 0; q < 4; q++) {
      float4 t = *(const float4*)&wdt_s[col][q * 4];
      w[cc][q*4+0] = t.x; w[cc][q*4+1] = t.y; w[cc][q*4+2] = t.z; w[cc][q*4+3] = t.w;
    }
    bb[cc] = 2.f * bdt[col];
  }
  #pragma unroll
  for (int rr = 0; rr < 8; rr++) {
    int row = rg * 8 + rr;
    float dr[16];
    #pragma unroll
    for (int q = 0; q < 4; q++) {
      float4 t = *(const float4*)&dt_s[row][q * 4];
      dr[q*4+0] = t.x; dr[q*4+1] = t.y; dr[q*4+2] = t.z; dr[q*4+3] = t.w;
    }
    #pragma unroll
    for (int cc = 0; cc < 4; cc++) {
      float s = bb[cc];
      #pragma unroll
      for (int k = 0; k < 16; k++) s = fmaf(dr[k], w[cc][k], s);
      dtv[(size_t)(m0 + row) * 256 + cc * 64 + c0] = softplus_f(s);
    }
  }
}

// ---------------------------------------------------------------------------
// Depthwise conv + SiLU, register-sliding-window (CT=8), bf16 in/out.
// idx = lt*192 + c4: each 64-lane wave spans one branch (192 = 3*64).
// ---------------------------------------------------------------------------
__global__ __launch_bounds__(256)
void conv_silu_k(const short* __restrict__ xyzb,
                 const float* __restrict__ wx, const float* __restrict__ bx,
                 const float* __restrict__ wy, const float* __restrict__ by,
                 const float* __restrict__ wz, const float* __restrict__ bz,
                 short* __restrict__ xcb, short* __restrict__ ycb,
                 short* __restrict__ zcb)
{
  int idx = blockIdx.x * 256 + threadIdx.x;
  int c4 = idx % 192;
  int lt = idx / 192;
  int row0 = lt * CT;
  int l0 = row0 & (SEQ - 1);

  float4 win[CT + 4];
  #pragma unroll
  for (int i = 0; i < CT + 4; i++) {
    int l = l0 + i - 2;
    if (l >= 0 && l < SEQ)
      win[i] = bf4_to_f4(*(const uint2*)(xyzb + (size_t)(row0 + i - 2) * 768 + c4 * 4));
    else
      win[i] = make_float4(0.f, 0.f, 0.f, 0.f);
  }

  if (c4 < 64) {
    int d = c4 * 4;
    float4 w  = *(const float4*)&wx[d];
    float4 bb = *(const float4*)&bx[d];
    #pragma unroll
    for (int t = 0; t < CT; t++) {
      float4 v = win[t + 2], o;
      o.x = silu_f(fmaf(v.x, w.x, bb.x));
      o.y = silu_f(fmaf(v.y, w.y, bb.y));
      o.z = silu_f(fmaf(v.z, w.z, bb.z));
      o.w = silu_f(fmaf(v.w, w.w, bb.w));
      *(short4*)&xcb[(size_t)(row0 + t) * 256 + d] = f4_to_bf4(o);
    }
  } else if (c4 < 128) {
    int d = (c4 - 64) * 4;
    float wq[4][3];
    #pragma unroll
    for (int q = 0; q < 4; q++)
      #pragma unroll
      for (int j = 0; j < 3; j++) wq[q][j] = wy[(d + q) * 3 + j];
    float4 bb = *(const float4*)&by[d];
    #pragma unroll
    for (int t = 0; t < CT; t++) {
      float a0 = bb.x, a1 = bb.y, a2 = bb.z, a3 = bb.w;
      #pragma unroll
      for (int j = 0; j < 3; j++) {
        float4 v = win[t + 1 + j];
        a0 = fmaf(v.x, wq[0][j], a0);
        a1 = fmaf(v.y, wq[1][j], a1);
        a2 = fmaf(v.z, wq[2][j], a2);
        a3 = fmaf(v.w, wq[3][j], a3);
      }
      float4 o; o.x = silu_f(a0); o.y = silu_f(a1); o.z = silu_f(a2); o.w = silu_f(a3);
      *(short4*)&ycb[(size_t)(row0 + t) * 256 + d] = f4_to_bf4(o);
    }
  } else {
    int d = (c4 - 128) * 4;
    float wq[4][5];
    #pragma unroll
    for (int q = 0; q < 4; q++)
      #pragma unroll
      for (int j = 0; j < 5; j++) wq[q][j] = wz[(d + q) * 5 + j];
    float4 bb = *(const float4*)&bz[d];
    #pragma unroll
    for (int t = 0; t < CT; t++) {
      float a0 = bb.x, a1 = bb.y, a2 = bb.z, a3 = bb.w;
      #pragma unroll
      for (int j = 0; j < 5; j++) {
        float4 v = win[t + j];
        a0 = fmaf(v.x, wq[0][j], a0);
        a1 = fmaf(v.y, wq[1][j], a1);
        a2 = fmaf(v.z, wq[2][j], a2);
        a3 = fmaf(v.w, wq[3][j], a3);
      }
      float4 o; o.x = silu_f(a0); o.y = silu_f(a1); o.z = silu_f(a2); o.w = silu_f(a3);
      *(short4*)&zcb[(size_t)(row0 + t) * 256 + d] = f4_to_bf4(o);
    }
  }
}

// ---------------------------------------------------------------------------
// Chunked selective scan, t-unrolled x4, LDS transposed [channel][t].
// Pass C writeback fuses the p*y elementwise product (reads ycb).
// ---------------------------------------------------------------------------
template<bool PASSC>
__global__ __launch_bounds__(256)
void scan_k(const short* __restrict__ xcb,    // u (bf16), (MT,256)
            const float* __restrict__ dtv,    // delta, (MT,256)
            const float* __restrict__ xdbl,   // (MT,48): [dt_r | B | C]
            const float* __restrict__ A_log,
            const float* __restrict__ Dp,
            const float* __restrict__ Hstart,
            float* __restrict__ Pbuf, float* __restrict__ hfbuf,
            const short* __restrict__ ycb,    // y-gate (bf16), pass C
            short* __restrict__ poutb)        // pass C out (bf16): p*yc
{
  __shared__ __align__(16) float2 du2_s[16 * 66];             // [ch][t]
  __shared__ __align__(16) float2 BC_s [PASSC ? 16 * 66 : 2]; // [n][t]
  __shared__ __align__(16) float  Bc_s [PASSC ? 4 : 16 * 68]; // [n][t] (pass A)
  __shared__ __align__(16) float  y_s  [PASSC ? 16 * 68 : 4]; // [ch][t]
  const int tid = threadIdx.x;
  const int n = tid & 15, dl = tid >> 4;
  const int ch = blockIdx.x;
  const int d0 = blockIdx.y * 16;
  const int b  = blockIdx.z;
  const int d  = d0 + dl;
  const int t0 = ch * LC;
  const size_t brow = (size_t)b * SEQ;

  float u_r[4];
  #pragma unroll
  for (int i = 0; i < 4; i++) {               // cooperative coalesced staging
    int t = (tid >> 4) + i * 16;
    int dd = tid & 15;
    size_t row = brow + t0 + t;
    float uval = bf2f(xcb[row * 256 + d0 + dd]);
    float dval = dtv[row * 256 + d0 + dd];
    du2_s[dd * 66 + t] = make_float2(dval, dval * uval);
    if constexpr (PASSC) {
      BC_s[dd * 66 + t] = make_float2(xdbl[row * 48 + 16 + dd],
                                      xdbl[row * 48 + 32 + dd]);
      u_r[i] = uval;
    } else {
      Bc_s[dd * 68 + t] = xdbl[row * 48 + 16 + dd];
    }
  }
  __syncthreads();

  const float A_dn = -__expf(A_log[d * NST + n]);
  const size_t cidx = (((size_t)b * DM + d) * NST + n) * NCHK + ch;

  float h = PASSC ? Hstart[cidx] : 0.f;
  float P = 1.f;
  for (int t4 = 0; t4 < LC; t4 += 4) {
    float4 a = *(const float4*)&du2_s[dl * 66 + t4];      // {dt0,du0,dt1,du1}
    float4 c = *(const float4*)&du2_s[dl * 66 + t4 + 2];  // {dt2,du2,dt3,du3}
    float dA[4], du[4];
    dA[0] = __expf(a.x * A_dn); du[0] = a.y;
    dA[1] = __expf(a.z * A_dn); du[1] = a.w;
    dA[2] = __expf(c.x * A_dn); du[2] = c.y;
    dA[3] = __expf(c.z * A_dn); du[3] = c.w;
    if constexpr (!PASSC) {
      float4 f = *(const float4*)&Bc_s[n * 68 + t4];      // B t4..t4+3
      float Bv[4] = {f.x, f.y, f.z, f.w};
      #pragma unroll
      for (int j = 0; j < 4; j++) {
        h = fmaf(dA[j], h, du[j] * Bv[j]);
        P *= dA[j];
      }
    } else {
      float4 e = *(const float4*)&BC_s[n * 66 + t4];      // {B0,C0,B1,C1}
      float4 g = *(const float4*)&BC_s[n * 66 + t4 + 2];  // {B2,C2,B3,C3}
      float Bv[4] = {e.x, e.z, g.x, g.z};
      float Cv[4] = {e.y, e.w, g.y, g.w};
      float yv[4];
      #pragma unroll
      for (int j = 0; j < 4; j++) {
        h = fmaf(dA[j], h, du[j] * Bv[j]);
        yv[j] = h * Cv[j];
      }
      #pragma unroll
      for (int j = 0; j < 4; j++) yv[j] = dpp_add_step<0x118>(yv[j]); // shr8
      #pragma unroll
      for (int j = 0; j < 4; j++) yv[j] = dpp_add_step<0x114>(yv[j]); // shr4
      #pragma unroll
      for (int j = 0; j < 4; j++) yv[j] = dpp_add_step<0x112>(yv[j]); // shr2
      #pragma unroll
      for (int j = 0; j < 4; j++) yv[j] = dpp_add_step<0x111>(yv[j]); // shr1
      if (n == 15)
        *(float4*)&y_s[dl * 68 + t4] = make_float4(yv[0], yv[1], yv[2], yv[3]);
    }
  }

  if constexpr (!PASSC) {
    Pbuf[cidx] = P;
    hfbuf[cidx] = h;
  } else {
    __syncthreads();
    const float Dval = Dp[d0 + n];
    #pragma unroll
    for (int i = 0; i < 4; i++) {             // coalesced writeback, fused *yc
      int t = (tid >> 4) + i * 16;
      size_t row = brow + t0 + t;
      float p = fmaf(Dval, u_r[i], y_s[n * 68 + t]);
      float yg = bf2f(ycb[row * 256 + d0 + n]);
      poutb[row * 256 + d0 + n] = f2bf(p * yg);
    }
  }
}

// serial combine across the 64 chunks; one thread per (b,d,n) chain
__global__ __launch_bounds__(256)
void scan_mid_k(const float* __restrict__ Pbuf, const float* __restrict__ hfbuf,
                float* __restrict__ Hstart)
{
  int tid = blockIdx.x * 256 + threadIdx.x;   // 0..16383
  size_t base = (size_t)tid * NCHK;
  float H = 0.f;
  for (int c = 0; c < NCHK; c++) {
    Hstart[base + c] = H;
    H = Pbuf[base + c] * H + hfbuf[base + c];
  }
}

// ---------------------------------------------------------------------------
extern "C" void kernel_launch(void* const* d_in, const int* in_sizes, int n_in,
                              void* d_out, int out_size, void* d_ws, size_t ws_size,
                              hipStream_t stream)
{
  const float* hs    = (const float*)d_in[0];
  const float* w_in  = (const float*)d_in[1];
  const float* w_xp  = (const float*)d_in[2];
  const float* w_dt  = (const float*)d_in[3];
  const float* b_dt  = (const float*)d_in[4];
  const float* A_log = (const float*)d_in[5];
  const float* Dp    = (const float*)d_in[6];
  const float* w_o1  = (const float*)d_in[7];
  const float* cwx   = (const float*)d_in[8];
  const float* cbx   = (const float*)d_in[9];
  const float* cwy   = (const float*)d_in[10];
  const float* cby   = (const float*)d_in[11];
  const float* cwz   = (const float*)d_in[12];
  const float* cbz   = (const float*)d_in[13];

  char* wsb = (char*)d_ws;
  short* xyzb = (short*)wsb;                            // MT*768 bf16
  short* xcb  = (short*)(wsb + (size_t)MT * 768 * 2);   // MT*256 bf16
  short* ycb  = xcb + (size_t)MT * 256;
  short* zcb  = ycb + (size_t)MT * 256;
  short* pbufb= zcb + (size_t)MT * 256;                 // p*yc (bf16)
  short* w_in_b = pbufb + (size_t)MT * 256;             // 768*256 bf16
  short* w_o1_b = w_in_b + 768 * 256;                   // 256*256 bf16
  short* hsb  = w_o1_b + 256 * 256;                     // MT*256 bf16
  float* xdbl = (float*)(hsb + (size_t)MT * 256 + 128); // MT*48 fp32
  float* dtv  = xdbl + (size_t)MT * 48;                 // MT*256 fp32
  float* Pb   = dtv  + (size_t)MT * 256;                // 1M fp32
  float* hf   = Pb   + (size_t)B_SZ * DM * NST * NCHK;
  float* Hs   = hf   + (size_t)B_SZ * DM * NST * NCHK;

  dim3 blk(256);

  // K0: weights + hs -> bf16  (1,114,112 float4 units / 256 = 4352 blocks)
  cvt_in_k<<<dim3(4352), blk, 0, stream>>>(w_in, w_o1, hs, w_in_b, w_o1_b, hsb);

  // K1: xyz = hs @ in_proj_w^T  (bf16 MFMA, both sides pure-copy staging)
  mfma_gemm_k<0, true><<<dim3(MT / 128, 768 / 128), blk, 0, stream>>>(
      hsb, w_in_b, xyzb, 768, 256, nullptr, nullptr, nullptr);

  // K2: depthwise conv + SiLU -> xcb, ycb, zcb (bf16), CT=8
  conv_silu_k<<<dim3((MT / CT) * 192 / 256), blk, 0, stream>>>(
      xyzb, cwx, cbx, cwy, cby, cwz, cbz, xcb, ycb, zcb);

  // K3+K4 fused
  gemm34_k<<<dim3(MT / 32), blk, 0, stream>>>(
      xcb, w_xp, w_dt, b_dt, xdbl, dtv);

  // K5-7: chunked selective scan -> pbufb = (scan out)*yc (bf16)
  scan_k<false><<<dim3(NCHK, DM / 16, B_SZ), blk, 0, stream>>>(
      xcb, dtv, xdbl, A_log, Dp, nullptr, Pb, hf, nullptr, nullptr);
  scan_mid_k<<<dim3((B_SZ * DM * NST) / 256), blk, 0, stream>>>(Pb, hf, Hs);
  scan_k<true><<<dim3(NCHK, DM / 16, B_SZ), blk, 0, stream>>>(
      xcb, dtv, xdbl, A_log, Dp, Hs, nullptr, nullptr, ycb, pbufb);

  // K8: out = (pbufb @ out_proj1_w^T) * zc * cwx + cbx  (fp32 out)
  mfma_gemm_k<2, false><<<dim3(MT / 128, 256 / 128), blk, 0, stream>>>(
      pbufb, w_o1_b, d_out, 256, 256, cbx, zcb, cwx);
}

// Round 15
// 208.341 us; speedup vs baseline: 7.0045x; 1.0091x over previous
//
#include <hip/hip_runtime.h>
#include <hip/hip_bf16.h>
#include <math.h>

typedef __hip_bfloat16 bf16;
typedef __attribute__((ext_vector_type(8))) short bf16x8;
typedef __attribute__((ext_vector_type(4))) float f32x4;

#define B_SZ 4
#define SEQ  4096
#define DM   256
#define NST  16
#define NCHK 64
#define LC   (SEQ/NCHK)      /* 64 */
#define MT   (B_SZ*SEQ)      /* 16384 rows of (b,l) */
#define CT   4               /* l-tile per conv thread */

__device__ __forceinline__ float silu_f(float v){ return v / (1.f + __expf(-v)); }
__device__ __forceinline__ float softplus_f(float v){
  return (v > 15.f) ? v : __logf(1.f + __expf(v));
}
__device__ __forceinline__ short f2bf(float f){
  union { bf16 h; short s; } u; u.h = __float2bfloat16(f); return u.s;
}
__device__ __forceinline__ float bf2f(short s){
  union { unsigned int i; float f; } v;
  v.i = ((unsigned int)(unsigned short)s) << 16; return v.f;
}
__device__ __forceinline__ float4 bf4_to_f4(uint2 q){
  float4 f;
  f.x = bf2f((short)(q.x & 0xffffu)); f.y = bf2f((short)(q.x >> 16));
  f.z = bf2f((short)(q.y & 0xffffu)); f.w = bf2f((short)(q.y >> 16));
  return f;
}
__device__ __forceinline__ short4 f4_to_bf4(float4 f){
  short4 s; s.x = f2bf(f.x); s.y = f2bf(f.y); s.z = f2bf(f.z); s.w = f2bf(f.w);
  return s;
}

// async global->LDS 16B copy (no VGPR round-trip). LDS side must be
// wave-uniform base + lane*16 (m104/m108); global side is per-lane.
__device__ __forceinline__ void async_cp16(const short* g, short* l){
  __builtin_amdgcn_global_load_lds(
      (const __attribute__((address_space(1))) unsigned int*)g,
      (__attribute__((address_space(3))) unsigned int*)l, 16, 0, 0);
}

// DPP row_shr:N add step; after N=8,4,2,1 lane 15 of each row = row sum.
template<int CTRL>
__device__ __forceinline__ float dpp_add_step(float v){
  int x = __builtin_amdgcn_update_dpp(0, __float_as_int(v), CTRL, 0xf, 0xf, true);
  return v + __int_as_float(x);
}

// ---------------------------------------------------------------------------
// Input pre-conversion to bf16: w_in (768x256), w_o1 (256x256), hs (MT x 256).
// ---------------------------------------------------------------------------
__global__ __launch_bounds__(256)
void cvt_in_k(const float* __restrict__ w_in, const float* __restrict__ w_o1,
              const float* __restrict__ hs,
              short* __restrict__ w_in_b, short* __restrict__ w_o1_b,
              short* __restrict__ hsb)
{
  int i = blockIdx.x * 256 + threadIdx.x;     // 0..1114111
  if (i < 49152) {
    float4 q = *(const float4*)&w_in[i * 4];
    *(short4*)&w_in_b[i * 4] = f4_to_bf4(q);
  } else if (i < 65536) {
    int j = i - 49152;
    float4 q = *(const float4*)&w_o1[j * 4];
    *(short4*)&w_o1_b[j * 4] = f4_to_bf4(q);
  } else {
    int j = i - 65536;                        // 0..1048575
    float4 q = *(const float4*)&hs[(size_t)j * 4];
    *(short4*)&hsb[(size_t)j * 4] = f4_to_bf4(q);
  }
}

// ---------------------------------------------------------------------------
// MFMA bf16 GEMM, global_load_lds staging. Tile 128x128, BK=64.
// LDS unpadded [row][64] shorts; chunk c of row r is stored at slot
// c ^ (r&7) -- swizzle applied on the GLOBAL fetch address (per-lane free),
// LDS writes stay wave-contiguous as the DMA requires. Fragment reads:
// slot (ks*4+quad)^(l16&7) -> all 8 16B-groups per 8 lanes, conflict-free.
// Grid (m-tiles, n-tiles): m on blockIdx.x (XCD L2 reuse for A).
// EPI 0: plain store. EPI 2: (acc * zc[m,n] * cwx[n] + bias[n]) (zc bf16).
// ---------------------------------------------------------------------------
template<int EPI, bool OBF>
__global__ __launch_bounds__(256)
void mfma_gemm_k(const short* __restrict__ Av, const short* __restrict__ Bw,
                 void* __restrict__ Outv, int N, int K,
                 const float* __restrict__ bias, const short* __restrict__ zc,
                 const float* __restrict__ cwx)
{
  constexpr int BM = 128, BN = 128, BK = 64;
  __shared__ short As[BM * BK];        // 16 KB, unpadded (DMA-contiguous)
  __shared__ short Bs[BN * BK];        // 16 KB
  const int tid  = threadIdx.x;
  const int wave = tid >> 6, lane = tid & 63;
  const int quad = lane >> 4, l16 = lane & 15;
  const int wm = (wave & 1) * 64, wn = (wave >> 1) * 64;
  const int m0 = blockIdx.x * BM, n0 = blockIdx.y * BN;

  f32x4 acc[4][4] = {};

  for (int k0 = 0; k0 < K; k0 += BK) {
    #pragma unroll
    for (int p = 0; p < 4; p++) {       // 1024 chunks each side / 256 thr
      int id = p * 256 + tid;
      int row = id >> 3, slot = id & 7;
      int gch = slot ^ (row & 7);       // swizzled global chunk
      async_cp16(Av + (size_t)(m0 + row) * K + k0 + gch * 8,
                 &As[row * 64 + slot * 8]);
      async_cp16(Bw + (size_t)(n0 + row) * K + k0 + gch * 8,
                 &Bs[row * 64 + slot * 8]);
    }
    __syncthreads();                    // drains vmcnt (DMA) for all waves
    #pragma unroll
    for (int ks = 0; ks < 2; ks++) {    // two 32-k steps per BK=64
      bf16x8 fa[4], fb[4];
      #pragma unroll
      for (int i = 0; i < 4; i++) {
        int sa = (ks * 4 + quad) ^ (l16 & 7);
        fa[i] = *(const bf16x8*)&As[(wm + i * 16 + l16) * 64 + sa * 8];
        fb[i] = *(const bf16x8*)&Bs[(wn + i * 16 + l16) * 64 + sa * 8];
      }
      #pragma unroll
      for (int i = 0; i < 4; i++)
        #pragma unroll
        for (int j = 0; j < 4; j++)
          acc[i][j] = __builtin_amdgcn_mfma_f32_16x16x32_bf16(fa[i], fb[j], acc[i][j], 0, 0, 0);
    }
    __syncthreads();
  }

  #pragma unroll
  for (int i = 0; i < 4; i++) {
    #pragma unroll
    for (int j = 0; j < 4; j++) {
      int n = n0 + wn + j * 16 + l16;
      #pragma unroll
      for (int r = 0; r < 4; r++) {
        int m = m0 + wm + i * 16 + quad * 4 + r;
        float v = acc[i][j][r];
        if constexpr (EPI == 2)
          v = v * bf2f(zc[(size_t)m * N + n]) * cwx[n] + bias[n];
        if constexpr (OBF) ((short*)Outv)[(size_t)m * N + n] = f2bf(v);
        else               ((float*)Outv)[(size_t)m * N + n] = v;
      }
    }
  }
}

// ---------------------------------------------------------------------------
// Fused K3+K4 (TM=32): xdbl = xc @ x_proj_w^T; dtv = softplus(dt_r@wdt^T+2b).
// ---------------------------------------------------------------------------
__global__ __launch_bounds__(256)
void gemm34_k(const short* __restrict__ xcb,
              const float* __restrict__ Bw,
              const float* __restrict__ wdt,
              const float* __restrict__ bdt,
              float* __restrict__ xdbl,
              float* __restrict__ dtv)
{
  constexpr int TM = 32, TK = 16, NN = 48;
  __shared__ __align__(16) float As[TK][TM + 4];
  __shared__ __align__(16) float Bs[TK][64 + 4];
  __shared__ __align__(16) float dt_s[TM][20];
  __shared__ __align__(16) float wdt_s[256][20];
  const int tid = threadIdx.x;
  const int tn = tid & 15, tm = tid >> 4;
  const int m0 = blockIdx.x * TM;
  float acc[2][4] = {};
  const int mlA = tid >> 3, kdA = (tid & 7) * 2;
  const int mlB = tid >> 2, kqB = (tid & 3) * 4;

  {
    float4 q0 = *(const float4*)&wdt[tid * 16 + 0];
    float4 q1 = *(const float4*)&wdt[tid * 16 + 4];
    float4 q2 = *(const float4*)&wdt[tid * 16 + 8];
    float4 q3 = *(const float4*)&wdt[tid * 16 + 12];
    *(float4*)&wdt_s[tid][0]  = q0;
    *(float4*)&wdt_s[tid][4]  = q1;
    *(float4*)&wdt_s[tid][8]  = q2;
    *(float4*)&wdt_s[tid][12] = q3;
  }

  for (int k0 = 0; k0 < 256; k0 += TK) {
    {
      size_t off = (size_t)(m0 + mlA) * 256 + k0 + kdA;
      unsigned int v = *(const unsigned int*)(xcb + off);
      As[kdA + 0][mlA] = bf2f((short)(v & 0xffffu));
      As[kdA + 1][mlA] = bf2f((short)(v >> 16));
    }
    {
      float v0 = 0.f, v1 = 0.f, v2 = 0.f, v3 = 0.f;
      if (mlB < NN) {
        float4 q = *(const float4*)(Bw + (size_t)mlB * 256 + k0 + kqB);
        v0 = q.x; v1 = q.y; v2 = q.z; v3 = q.w;
      }
      Bs[kqB+0][mlB] = v0; Bs[kqB+1][mlB] = v1; Bs[kqB+2][mlB] = v2; Bs[kqB+3][mlB] = v3;
    }
    __syncthreads();
    #pragma unroll
    for (int k = 0; k < TK; k++) {
      float2 av = *(const float2*)&As[k][tm << 1];
      float4 bv = *(const float4*)&Bs[k][tn << 2];
      float a[2] = {av.x, av.y};
      float b[4] = {bv.x, bv.y, bv.z, bv.w};
      #pragma unroll
      for (int i = 0; i < 2; i++)
        #pragma unroll
        for (int j = 0; j < 4; j++)
          acc[i][j] = fmaf(a[i], b[j], acc[i][j]);
    }
    __syncthreads();
  }

  #pragma unroll
  for (int i = 0; i < 2; i++) {
    int m = m0 + (tm << 1) + i;
    #pragma unroll
    for (int j = 0; j < 4; j++) {
      int n = (tn << 2) + j;
      float v = acc[i][j];
      if (n < NN) xdbl[(size_t)m * NN + n] = v;
      if (tn < 4) dt_s[(tm << 1) + i][n] = v;
    }
  }
  __syncthreads();

  const int c0 = tid & 63, rg = tid >> 6;
  float w[4][16];
  float bb[4];
  #pragma unroll
  for (int cc = 0; cc < 4; cc++) {
    int col = cc * 64 + c0;
    #pragma unroll
    for (int q = 0; q < 4; q++) {
      float4 t = *(const float4*)&wdt_s[col][q * 4];
      w[cc][q*4+0] = t.x; w[cc][q*4+1] = t.y; w[cc][q*4+2] = t.z; w[cc][q*4+3] = t.w;
    }
    bb[cc] = 2.f * bdt[col];
  }
  #pragma unroll
  for (int rr = 0; rr < 8; rr++) {
    int row = rg * 8 + rr;
    float dr[16];
    #pragma unroll
    for (int q = 0; q < 4; q++) {
      float4 t = *(const float4*)&dt_s[row][q * 4];
      dr[q*4+0] = t.x; dr[q*4+1] = t.y; dr[q*4+2] = t.z; dr[q*4+3] = t.w;
    }
    #pragma unroll
    for (int cc = 0; cc < 4; cc++) {
      float s = bb[cc];
      #pragma unroll
      for (int k = 0; k < 16; k++) s = fmaf(dr[k], w[cc][k], s);
      dtv[(size_t)(m0 + row) * 256 + cc * 64 + c0] = softplus_f(s);
    }
  }
}

// ---------------------------------------------------------------------------
// Depthwise conv + SiLU, register-sliding-window (CT=4), bf16 in/out.
// ---------------------------------------------------------------------------
__global__ __launch_bounds__(256)
void conv_silu_k(const short* __restrict__ xyzb,
                 const float* __restrict__ wx, const float* __restrict__ bx,
                 const float* __restrict__ wy, const float* __restrict__ by,
                 const float* __restrict__ wz, const float* __restrict__ bz,
                 short* __restrict__ xcb, short* __restrict__ ycb,
                 short* __restrict__ zcb)
{
  int idx = blockIdx.x * 256 + threadIdx.x;
  int c4 = idx % 192;
  int lt = idx / 192;
  int row0 = lt * CT;
  int l0 = row0 & (SEQ - 1);

  float4 win[CT + 4];
  #pragma unroll
  for (int i = 0; i < CT + 4; i++) {
    int l = l0 + i - 2;
    if (l >= 0 && l < SEQ)
      win[i] = bf4_to_f4(*(const uint2*)(xyzb + (size_t)(row0 + i - 2) * 768 + c4 * 4));
    else
      win[i] = make_float4(0.f, 0.f, 0.f, 0.f);
  }

  if (c4 < 64) {
    int d = c4 * 4;
    float4 w  = *(const float4*)&wx[d];
    float4 bb = *(const float4*)&bx[d];
    #pragma unroll
    for (int t = 0; t < CT; t++) {
      float4 v = win[t + 2], o;
      o.x = silu_f(fmaf(v.x, w.x, bb.x));
      o.y = silu_f(fmaf(v.y, w.y, bb.y));
      o.z = silu_f(fmaf(v.z, w.z, bb.z));
      o.w = silu_f(fmaf(v.w, w.w, bb.w));
      *(short4*)&xcb[(size_t)(row0 + t) * 256 + d] = f4_to_bf4(o);
    }
  } else if (c4 < 128) {
    int d = (c4 - 64) * 4;
    float wq[4][3];
    #pragma unroll
    for (int q = 0; q < 4; q++)
      #pragma unroll
      for (int j = 0; j < 3; j++) wq[q][j] = wy[(d + q) * 3 + j];
    float4 bb = *(const float4*)&by[d];
    #pragma unroll
    for (int t = 0; t < CT; t++) {
      float a0 = bb.x, a1 = bb.y, a2 = bb.z, a3 = bb.w;
      #pragma unroll
      for (int j = 0; j < 3; j++) {
        float4 v = win[t + 1 + j];
        a0 = fmaf(v.x, wq[0][j], a0);
        a1 = fmaf(v.y, wq[1][j], a1);
        a2 = fmaf(v.z, wq[2][j], a2);
        a3 = fmaf(v.w, wq[3][j], a3);
      }
      float4 o; o.x = silu_f(a0); o.y = silu_f(a1); o.z = silu_f(a2); o.w = silu_f(a3);
      *(short4*)&ycb[(size_t)(row0 + t) * 256 + d] = f4_to_bf4(o);
    }
  } else {
    int d = (c4 - 128) * 4;
    float wq[4][5];
    #pragma unroll
    for (int q = 0; q < 4; q++)
      #pragma unroll
      for (int j = 0; j < 5; j++) wq[q][j] = wz[(d + q) * 5 + j];
    float4 bb = *(const float4*)&bz[d];
    #pragma unroll
    for (int t = 0; t < CT; t++) {
      float a0 = bb.x, a1 = bb.y, a2 = bb.z, a3 = bb.w;
      #pragma unroll
      for (int j = 0; j < 5; j++) {
        float4 v = win[t + j];
        a0 = fmaf(v.x, wq[0][j], a0);
        a1 = fmaf(v.y, wq[1][j], a1);
        a2 = fmaf(v.z, wq[2][j], a2);
        a3 = fmaf(v.w, wq[3][j], a3);
      }
      float4 o; o.x = silu_f(a0); o.y = silu_f(a1); o.z = silu_f(a2); o.w = silu_f(a3);
      *(short4*)&zcb[(size_t)(row0 + t) * 256 + d] = f4_to_bf4(o);
    }
  }
}

// ---------------------------------------------------------------------------
// Chunked selective scan, t-unrolled x4, LDS transposed [channel][t].
// Pass C writeback fuses the p*y elementwise product (reads ycb).
// ---------------------------------------------------------------------------
template<bool PASSC>
__global__ __launch_bounds__(256)
void scan_k(const short* __restrict__ xcb,    // u (bf16), (MT,256)
            const float* __restrict__ dtv,    // delta, (MT,256)
            const float* __restrict__ xdbl,   // (MT,48): [dt_r | B | C]
            const float* __restrict__ A_log,
            const float* __restrict__ Dp,
            const float* __restrict__ Hstart,
            float* __restrict__ Pbuf, float* __restrict__ hfbuf,
            const short* __restrict__ ycb,    // y-gate (bf16), pass C
            short* __restrict__ poutb)        // pass C out (bf16): p*yc
{
  __shared__ __align__(16) float2 du2_s[16 * 66];             // [ch][t]
  __shared__ __align__(16) float2 BC_s [PASSC ? 16 * 66 : 2]; // [n][t]
  __shared__ __align__(16) float  Bc_s [PASSC ? 4 : 16 * 68]; // [n][t] (pass A)
  __shared__ __align__(16) float  y_s  [PASSC ? 16 * 68 : 4]; // [ch][t]
  const int tid = threadIdx.x;
  const int n = tid & 15, dl = tid >> 4;
  const int ch = blockIdx.x;
  const int d0 = blockIdx.y * 16;
  const int b  = blockIdx.z;
  const int d  = d0 + dl;
  const int t0 = ch * LC;
  const size_t brow = (size_t)b * SEQ;

  float u_r[4];
  #pragma unroll
  for (int i = 0; i < 4; i++) {               // cooperative coalesced staging
    int t = (tid >> 4) + i * 16;
    int dd = tid & 15;
    size_t row = brow + t0 + t;
    float uval = bf2f(xcb[row * 256 + d0 + dd]);
    float dval = dtv[row * 256 + d0 + dd];
    du2_s[dd * 66 + t] = make_float2(dval, dval * uval);
    if constexpr (PASSC) {
      BC_s[dd * 66 + t] = make_float2(xdbl[row * 48 + 16 + dd],
                                      xdbl[row * 48 + 32 + dd]);
      u_r[i] = uval;
    } else {
      Bc_s[dd * 68 + t] = xdbl[row * 48 + 16 + dd];
    }
  }
  __syncthreads();

  const float A_dn = -__expf(A_log[d * NST + n]);
  const size_t cidx = (((size_t)b * DM + d) * NST + n) * NCHK + ch;

  float h = PASSC ? Hstart[cidx] : 0.f;
  float P = 1.f;
  for (int t4 = 0; t4 < LC; t4 += 4) {
    float4 a = *(const float4*)&du2_s[dl * 66 + t4];      // {dt0,du0,dt1,du1}
    float4 c = *(const float4*)&du2_s[dl * 66 + t4 + 2];  // {dt2,du2,dt3,du3}
    float dA[4], du[4];
    dA[0] = __expf(a.x * A_dn); du[0] = a.y;
    dA[1] = __expf(a.z * A_dn); du[1] = a.w;
    dA[2] = __expf(c.x * A_dn); du[2] = c.y;
    dA[3] = __expf(c.z * A_dn); du[3] = c.w;
    if constexpr (!PASSC) {
      float4 f = *(const float4*)&Bc_s[n * 68 + t4];      // B t4..t4+3
      float Bv[4] = {f.x, f.y, f.z, f.w};
      #pragma unroll
      for (int j = 0; j < 4; j++) {
        h = fmaf(dA[j], h, du[j] * Bv[j]);
        P *= dA[j];
      }
    } else {
      float4 e = *(const float4*)&BC_s[n * 66 + t4];      // {B0,C0,B1,C1}
      float4 g = *(const float4*)&BC_s[n * 66 + t4 + 2];  // {B2,C2,B3,C3}
      float Bv[4] = {e.x, e.z, g.x, g.z};
      float Cv[4] = {e.y, e.w, g.y, g.w};
      float yv[4];
      #pragma unroll
      for (int j = 0; j < 4; j++) {
        h = fmaf(dA[j], h, du[j] * Bv[j]);
        yv[j] = h * Cv[j];
      }
      #pragma unroll
      for (int j = 0; j < 4; j++) yv[j] = dpp_add_step<0x118>(yv[j]); // shr8
      #pragma unroll
      for (int j = 0; j < 4; j++) yv[j] = dpp_add_step<0x114>(yv[j]); // shr4
      #pragma unroll
      for (int j = 0; j < 4; j++) yv[j] = dpp_add_step<0x112>(yv[j]); // shr2
      #pragma unroll
      for (int j = 0; j < 4; j++) yv[j] = dpp_add_step<0x111>(yv[j]); // shr1
      if (n == 15)
        *(float4*)&y_s[dl * 68 + t4] = make_float4(yv[0], yv[1], yv[2], yv[3]);
    }
  }

  if constexpr (!PASSC) {
    Pbuf[cidx] = P;
    hfbuf[cidx] = h;
  } else {
    __syncthreads();
    const float Dval = Dp[d0 + n];
    #pragma unroll
    for (int i = 0; i < 4; i++) {             // coalesced writeback, fused *yc
      int t = (tid >> 4) + i * 16;
      size_t row = brow + t0 + t;
      float p = fmaf(Dval, u_r[i], y_s[n * 68 + t]);
      float yg = bf2f(ycb[row * 256 + d0 + n]);
      poutb[row * 256 + d0 + n] = f2bf(p * yg);
    }
  }
}

// serial combine across the 64 chunks; one thread per (b,d,n) chain
__global__ __launch_bounds__(256)
void scan_mid_k(const float* __restrict__ Pbuf, const float* __restrict__ hfbuf,
                float* __restrict__ Hstart)
{
  int tid = blockIdx.x * 256 + threadIdx.x;   // 0..16383
  size_t base = (size_t)tid * NCHK;
  float H = 0.f;
  for (int c = 0; c < NCHK; c++) {
    Hstart[base + c] = H;
    H = Pbuf[base + c] * H + hfbuf[base + c];
  }
}

// ---------------------------------------------------------------------------
extern "C" void kernel_launch(void* const* d_in, const int* in_sizes, int n_in,
                              void* d_out, int out_size, void* d_ws, size_t ws_size,
                              hipStream_t stream)
{
  const float* hs    = (const float*)d_in[0];
  const float* w_in  = (const float*)d_in[1];
  const float* w_xp  = (const float*)d_in[2];
  const float* w_dt  = (const float*)d_in[3];
  const float* b_dt  = (const float*)d_in[4];
  const float* A_log = (const float*)d_in[5];
  const float* Dp    = (const float*)d_in[6];
  const float* w_o1  = (const float*)d_in[7];
  const float* cwx   = (const float*)d_in[8];
  const float* cbx   = (const float*)d_in[9];
  const float* cwy   = (const float*)d_in[10];
  const float* cby   = (const float*)d_in[11];
  const float* cwz   = (const float*)d_in[12];
  const float* cbz   = (const float*)d_in[13];

  char* wsb = (char*)d_ws;
  short* xyzb = (short*)wsb;                            // MT*768 bf16
  short* xcb  = (short*)(wsb + (size_t)MT * 768 * 2);   // MT*256 bf16
  short* ycb  = xcb + (size_t)MT * 256;
  short* zcb  = ycb + (size_t)MT * 256;
  short* pbufb= zcb + (size_t)MT * 256;                 // p*yc (bf16)
  short* w_in_b = pbufb + (size_t)MT * 256;             // 768*256 bf16
  short* w_o1_b = w_in_b + 768 * 256;                   // 256*256 bf16
  short* hsb  = w_o1_b + 256 * 256;                     // MT*256 bf16
  float* xdbl = (float*)(hsb + (size_t)MT * 256 + 128); // MT*48 fp32
  float* dtv  = xdbl + (size_t)MT * 48;                 // MT*256 fp32
  float* Pb   = dtv  + (size_t)MT * 256;                // 1M fp32
  float* hf   = Pb   + (size_t)B_SZ * DM * NST * NCHK;
  float* Hs   = hf   + (size_t)B_SZ * DM * NST * NCHK;

  dim3 blk(256);

  // K0: weights + hs -> bf16
  cvt_in_k<<<dim3(4352), blk, 0, stream>>>(w_in, w_o1, hs, w_in_b, w_o1_b, hsb);

  // K1: xyz = hs @ in_proj_w^T  (bf16 MFMA, global_load_lds staging)
  mfma_gemm_k<0, true><<<dim3(MT / 128, 768 / 128), blk, 0, stream>>>(
      hsb, w_in_b, xyzb, 768, 256, nullptr, nullptr, nullptr);

  // K2: depthwise conv + SiLU -> xcb, ycb, zcb (bf16), CT=4
  conv_silu_k<<<dim3((MT / CT) * 192 / 256), blk, 0, stream>>>(
      xyzb, cwx, cbx, cwy, cby, cwz, cbz, xcb, ycb, zcb);

  // K3+K4 fused
  gemm34_k<<<dim3(MT / 32), blk, 0, stream>>>(
      xcb, w_xp, w_dt, b_dt, xdbl, dtv);

  // K5-7: chunked selective scan -> pbufb = (scan out)*yc (bf16)
  scan_k<false><<<dim3(NCHK, DM / 16, B_SZ), blk, 0, stream>>>(
      xcb, dtv, xdbl, A_log, Dp, nullptr, Pb, hf, nullptr, nullptr);
  scan_mid_k<<<dim3((B_SZ * DM * NST) / 256), blk, 0, stream>>>(Pb, hf, Hs);
  scan_k<true><<<dim3(NCHK, DM / 16, B_SZ), blk, 0, stream>>>(
      xcb, dtv, xdbl, A_log, Dp, Hs, nullptr, nullptr, ycb, pbufb);

  // K8: out = (pbufb @ out_proj1_w^T) * zc * cwx + cbx  (fp32 out)
  mfma_gemm_k<2, false><<<dim3(MT / 128, 256 / 128), blk, 0, stream>>>(
      pbufb, w_o1_b, d_out, 256, 256, cbx, zcb, cwx);
}

// Round 16
// 201.461 us; speedup vs baseline: 7.2437x; 1.0342x over previous
//
#include <hip/hip_runtime.h>
#include <hip/hip_bf16.h>
#include <math.h>

typedef __hip_bfloat16 bf16;
typedef __attribute__((ext_vector_type(8))) short bf16x8;
typedef __attribute__((ext_vector_type(4))) float f32x4;

#define B_SZ 4
#define SEQ  4096
#define DM   256
#define NST  16
#define NCHK 64
#define LC   (SEQ/NCHK)      /* 64 */
#define MT   (B_SZ*SEQ)      /* 16384 rows of (b,l) */
#define CT   4               /* l-tile per conv thread */
#define NLIN (B_SZ*16*256)   /* 16384 scan chains */

__device__ __forceinline__ float silu_f(float v){ return v / (1.f + __expf(-v)); }
__device__ __forceinline__ float softplus_f(float v){
  return (v > 15.f) ? v : __logf(1.f + __expf(v));
}
__device__ __forceinline__ short f2bf(float f){
  union { bf16 h; short s; } u; u.h = __float2bfloat16(f); return u.s;
}
__device__ __forceinline__ float bf2f(short s){
  union { unsigned int i; float f; } v;
  v.i = ((unsigned int)(unsigned short)s) << 16; return v.f;
}
__device__ __forceinline__ float4 bf4_to_f4(uint2 q){
  float4 f;
  f.x = bf2f((short)(q.x & 0xffffu)); f.y = bf2f((short)(q.x >> 16));
  f.z = bf2f((short)(q.y & 0xffffu)); f.w = bf2f((short)(q.y >> 16));
  return f;
}
__device__ __forceinline__ short4 f4_to_bf4(float4 f){
  short4 s; s.x = f2bf(f.x); s.y = f2bf(f.y); s.z = f2bf(f.z); s.w = f2bf(f.w);
  return s;
}

// async global->LDS 16B copy (no VGPR round-trip). LDS side must be
// wave-uniform base + lane*16 (m104/m108); global side is per-lane.
__device__ __forceinline__ void async_cp16(const short* g, short* l){
  __builtin_amdgcn_global_load_lds(
      (const __attribute__((address_space(1))) unsigned int*)g,
      (__attribute__((address_space(3))) unsigned int*)l, 16, 0, 0);
}

// DPP row_shr:N add step; after N=8,4,2,1 lane 15 of each row = row sum.
template<int CTRL>
__device__ __forceinline__ float dpp_add_step(float v){
  int x = __builtin_amdgcn_update_dpp(0, __float_as_int(v), CTRL, 0xf, 0xf, true);
  return v + __int_as_float(x);
}

// ---------------------------------------------------------------------------
// Input pre-conversion to bf16: w_in (768x256), w_o1 (256x256), hs (MT x 256).
// ---------------------------------------------------------------------------
__global__ __launch_bounds__(256)
void cvt_in_k(const float* __restrict__ w_in, const float* __restrict__ w_o1,
              const float* __restrict__ hs,
              short* __restrict__ w_in_b, short* __restrict__ w_o1_b,
              short* __restrict__ hsb)
{
  int i = blockIdx.x * 256 + threadIdx.x;     // 0..1114111
  if (i < 49152) {
    float4 q = *(const float4*)&w_in[i * 4];
    *(short4*)&w_in_b[i * 4] = f4_to_bf4(q);
  } else if (i < 65536) {
    int j = i - 49152;
    float4 q = *(const float4*)&w_o1[j * 4];
    *(short4*)&w_o1_b[j * 4] = f4_to_bf4(q);
  } else {
    int j = i - 65536;                        // 0..1048575
    float4 q = *(const float4*)&hs[(size_t)j * 4];
    *(short4*)&hsb[(size_t)j * 4] = f4_to_bf4(q);
  }
}

// ---------------------------------------------------------------------------
// MFMA bf16 GEMM, global_load_lds staging. Tile 128x128, BK=64.
// XOR-swizzled LDS slots (applied on global fetch side); conflict-free b128
// fragment reads. Grid (m-tiles, n-tiles): m on blockIdx.x (XCD L2 reuse).
// EPI 0: plain store. EPI 2: (acc * zc[m,n] * cwx[n] + bias[n]) (zc bf16).
// ---------------------------------------------------------------------------
template<int EPI, bool OBF>
__global__ __launch_bounds__(256)
void mfma_gemm_k(const short* __restrict__ Av, const short* __restrict__ Bw,
                 void* __restrict__ Outv, int N, int K,
                 const float* __restrict__ bias, const short* __restrict__ zc,
                 const float* __restrict__ cwx)
{
  constexpr int BM = 128, BN = 128, BK = 64;
  __shared__ short As[BM * BK];        // 16 KB, unpadded (DMA-contiguous)
  __shared__ short Bs[BN * BK];        // 16 KB
  const int tid  = threadIdx.x;
  const int wave = tid >> 6, lane = tid & 63;
  const int quad = lane >> 4, l16 = lane & 15;
  const int wm = (wave & 1) * 64, wn = (wave >> 1) * 64;
  const int m0 = blockIdx.x * BM, n0 = blockIdx.y * BN;

  f32x4 acc[4][4] = {};

  for (int k0 = 0; k0 < K; k0 += BK) {
    #pragma unroll
    for (int p = 0; p < 4; p++) {       // 1024 chunks each side / 256 thr
      int id = p * 256 + tid;
      int row = id >> 3, slot = id & 7;
      int gch = slot ^ (row & 7);       // swizzled global chunk
      async_cp16(Av + (size_t)(m0 + row) * K + k0 + gch * 8,
                 &As[row * 64 + slot * 8]);
      async_cp16(Bw + (size_t)(n0 + row) * K + k0 + gch * 8,
                 &Bs[row * 64 + slot * 8]);
    }
    __syncthreads();                    // drains vmcnt (DMA) for all waves
    #pragma unroll
    for (int ks = 0; ks < 2; ks++) {    // two 32-k steps per BK=64
      bf16x8 fa[4], fb[4];
      #pragma unroll
      for (int i = 0; i < 4; i++) {
        int sa = (ks * 4 + quad) ^ (l16 & 7);
        fa[i] = *(const bf16x8*)&As[(wm + i * 16 + l16) * 64 + sa * 8];
        fb[i] = *(const bf16x8*)&Bs[(wn + i * 16 + l16) * 64 + sa * 8];
      }
      #pragma unroll
      for (int i = 0; i < 4; i++)
        #pragma unroll
        for (int j = 0; j < 4; j++)
          acc[i][j] = __builtin_amdgcn_mfma_f32_16x16x32_bf16(fa[i], fb[j], acc[i][j], 0, 0, 0);
    }
    __syncthreads();
  }

  #pragma unroll
  for (int i = 0; i < 4; i++) {
    #pragma unroll
    for (int j = 0; j < 4; j++) {
      int n = n0 + wn + j * 16 + l16;
      #pragma unroll
      for (int r = 0; r < 4; r++) {
        int m = m0 + wm + i * 16 + quad * 4 + r;
        float v = acc[i][j][r];
        if constexpr (EPI == 2)
          v = v * bf2f(zc[(size_t)m * N + n]) * cwx[n] + bias[n];
        if constexpr (OBF) ((short*)Outv)[(size_t)m * N + n] = f2bf(v);
        else               ((float*)Outv)[(size_t)m * N + n] = v;
      }
    }
  }
}

// ---------------------------------------------------------------------------
// Fused K3+K4 (TM=32): xdbl = xc @ x_proj_w^T; dtv = softplus(dt_r@wdt^T+2b).
// ---------------------------------------------------------------------------
__global__ __launch_bounds__(256)
void gemm34_k(const short* __restrict__ xcb,
              const float* __restrict__ Bw,
              const float* __restrict__ wdt,
              const float* __restrict__ bdt,
              float* __restrict__ xdbl,
              float* __restrict__ dtv)
{
  constexpr int TM = 32, TK = 16, NN = 48;
  __shared__ __align__(16) float As[TK][TM + 4];
  __shared__ __align__(16) float Bs[TK][64 + 4];
  __shared__ __align__(16) float dt_s[TM][20];
  __shared__ __align__(16) float wdt_s[256][20];
  const int tid = threadIdx.x;
  const int tn = tid & 15, tm = tid >> 4;
  const int m0 = blockIdx.x * TM;
  float acc[2][4] = {};
  const int mlA = tid >> 3, kdA = (tid & 7) * 2;
  const int mlB = tid >> 2, kqB = (tid & 3) * 4;

  {
    float4 q0 = *(const float4*)&wdt[tid * 16 + 0];
    float4 q1 = *(const float4*)&wdt[tid * 16 + 4];
    float4 q2 = *(const float4*)&wdt[tid * 16 + 8];
    float4 q3 = *(const float4*)&wdt[tid * 16 + 12];
    *(float4*)&wdt_s[tid][0]  = q0;
    *(float4*)&wdt_s[tid][4]  = q1;
    *(float4*)&wdt_s[tid][8]  = q2;
    *(float4*)&wdt_s[tid][12] = q3;
  }

  for (int k0 = 0; k0 < 256; k0 += TK) {
    {
      size_t off = (size_t)(m0 + mlA) * 256 + k0 + kdA;
      unsigned int v = *(const unsigned int*)(xcb + off);
      As[kdA + 0][mlA] = bf2f((short)(v & 0xffffu));
      As[kdA + 1][mlA] = bf2f((short)(v >> 16));
    }
    {
      float v0 = 0.f, v1 = 0.f, v2 = 0.f, v3 = 0.f;
      if (mlB < NN) {
        float4 q = *(const float4*)(Bw + (size_t)mlB * 256 + k0 + kqB);
        v0 = q.x; v1 = q.y; v2 = q.z; v3 = q.w;
      }
      Bs[kqB+0][mlB] = v0; Bs[kqB+1][mlB] = v1; Bs[kqB+2][mlB] = v2; Bs[kqB+3][mlB] = v3;
    }
    __syncthreads();
    #pragma unroll
    for (int k = 0; k < TK; k++) {
      float2 av = *(const float2*)&As[k][tm << 1];
      float4 bv = *(const float4*)&Bs[k][tn << 2];
      float a[2] = {av.x, av.y};
      float b[4] = {bv.x, bv.y, bv.z, bv.w};
      #pragma unroll
      for (int i = 0; i < 2; i++)
        #pragma unroll
        for (int j = 0; j < 4; j++)
          acc[i][j] = fmaf(a[i], b[j], acc[i][j]);
    }
    __syncthreads();
  }

  #pragma unroll
  for (int i = 0; i < 2; i++) {
    int m = m0 + (tm << 1) + i;
    #pragma unroll
    for (int j = 0; j < 4; j++) {
      int n = (tn << 2) + j;
      float v = acc[i][j];
      if (n < NN) xdbl[(size_t)m * NN + n] = v;
      if (tn < 4) dt_s[(tm << 1) + i][n] = v;
    }
  }
  __syncthreads();

  const int c0 = tid & 63, rg = tid >> 6;
  float w[4][16];
  float bb[4];
  #pragma unroll
  for (int cc = 0; cc < 4; cc++) {
    int col = cc * 64 + c0;
    #pragma unroll
    for (int q = 0; q < 4; q++) {
      float4 t = *(const float4*)&wdt_s[col][q * 4];
      w[cc][q*4+0] = t.x; w[cc][q*4+1] = t.y; w[cc][q*4+2] = t.z; w[cc][q*4+3] = t.w;
    }
    bb[cc] = 2.f * bdt[col];
  }
  #pragma unroll
  for (int rr = 0; rr < 8; rr++) {
    int row = rg * 8 + rr;
    float dr[16];
    #pragma unroll
    for (int q = 0; q < 4; q++) {
      float4 t = *(const float4*)&dt_s[row][q * 4];
      dr[q*4+0] = t.x; dr[q*4+1] = t.y; dr[q*4+2] = t.z; dr[q*4+3] = t.w;
    }
    #pragma unroll
    for (int cc = 0; cc < 4; cc++) {
      float s = bb[cc];
      #pragma unroll
      for (int k = 0; k < 16; k++) s = fmaf(dr[k], w[cc][k], s);
      dtv[(size_t)(m0 + row) * 256 + cc * 64 + c0] = softplus_f(s);
    }
  }
}

// ---------------------------------------------------------------------------
// Depthwise conv + SiLU, register-sliding-window (CT=4), bf16 in/out.
// ---------------------------------------------------------------------------
__global__ __launch_bounds__(256)
void conv_silu_k(const short* __restrict__ xyzb,
                 const float* __restrict__ wx, const float* __restrict__ bx,
                 const float* __restrict__ wy, const float* __restrict__ by,
                 const float* __restrict__ wz, const float* __restrict__ bz,
                 short* __restrict__ xcb, short* __restrict__ ycb,
                 short* __restrict__ zcb)
{
  int idx = blockIdx.x * 256 + threadIdx.x;
  int c4 = idx % 192;
  int lt = idx / 192;
  int row0 = lt * CT;
  int l0 = row0 & (SEQ - 1);

  float4 win[CT + 4];
  #pragma unroll
  for (int i = 0; i < CT + 4; i++) {
    int l = l0 + i - 2;
    if (l >= 0 && l < SEQ)
      win[i] = bf4_to_f4(*(const uint2*)(xyzb + (size_t)(row0 + i - 2) * 768 + c4 * 4));
    else
      win[i] = make_float4(0.f, 0.f, 0.f, 0.f);
  }

  if (c4 < 64) {
    int d = c4 * 4;
    float4 w  = *(const float4*)&wx[d];
    float4 bb = *(const float4*)&bx[d];
    #pragma unroll
    for (int t = 0; t < CT; t++) {
      float4 v = win[t + 2], o;
      o.x = silu_f(fmaf(v.x, w.x, bb.x));
      o.y = silu_f(fmaf(v.y, w.y, bb.y));
      o.z = silu_f(fmaf(v.z, w.z, bb.z));
      o.w = silu_f(fmaf(v.w, w.w, bb.w));
      *(short4*)&xcb[(size_t)(row0 + t) * 256 + d] = f4_to_bf4(o);
    }
  } else if (c4 < 128) {
    int d = (c4 - 64) * 4;
    float wq[4][3];
    #pragma unroll
    for (int q = 0; q < 4; q++)
      #pragma unroll
      for (int j = 0; j < 3; j++) wq[q][j] = wy[(d + q) * 3 + j];
    float4 bb = *(const float4*)&by[d];
    #pragma unroll
    for (int t = 0; t < CT; t++) {
      float a0 = bb.x, a1 = bb.y, a2 = bb.z, a3 = bb.w;
      #pragma unroll
      for (int j = 0; j < 3; j++) {
        float4 v = win[t + 1 + j];
        a0 = fmaf(v.x, wq[0][j], a0);
        a1 = fmaf(v.y, wq[1][j], a1);
        a2 = fmaf(v.z, wq[2][j], a2);
        a3 = fmaf(v.w, wq[3][j], a3);
      }
      float4 o; o.x = silu_f(a0); o.y = silu_f(a1); o.z = silu_f(a2); o.w = silu_f(a3);
      *(short4*)&ycb[(size_t)(row0 + t) * 256 + d] = f4_to_bf4(o);
    }
  } else {
    int d = (c4 - 128) * 4;
    float wq[4][5];
    #pragma unroll
    for (int q = 0; q < 4; q++)
      #pragma unroll
      for (int j = 0; j < 5; j++) wq[q][j] = wz[(d + q) * 5 + j];
    float4 bb = *(const float4*)&bz[d];
    #pragma unroll
    for (int t = 0; t < CT; t++) {
      float a0 = bb.x, a1 = bb.y, a2 = bb.z, a3 = bb.w;
      #pragma unroll
      for (int j = 0; j < 5; j++) {
        float4 v = win[t + j];
        a0 = fmaf(v.x, wq[0][j], a0);
        a1 = fmaf(v.y, wq[1][j], a1);
        a2 = fmaf(v.z, wq[2][j], a2);
        a3 = fmaf(v.w, wq[3][j], a3);
      }
      float4 o; o.x = silu_f(a0); o.y = silu_f(a1); o.z = silu_f(a2); o.w = silu_f(a3);
      *(short4*)&zcb[(size_t)(row0 + t) * 256 + d] = f4_to_bf4(o);
    }
  }
}

// ---------------------------------------------------------------------------
// Chunked selective scan, t-unrolled x4, LDS transposed [channel][t].
// Chunk-state arrays use TRANSPOSED layout cidx = ch*NLIN + lin (lin =
// (b*16+dg)*256 + tid) so all inter-pass stores/loads are lane-coalesced.
// Pass C writeback fuses the p*y elementwise product (reads ycb).
// ---------------------------------------------------------------------------
template<bool PASSC>
__global__ __launch_bounds__(256)
void scan_k(const short* __restrict__ xcb,    // u (bf16), (MT,256)
            const float* __restrict__ dtv,    // delta, (MT,256)
            const float* __restrict__ xdbl,   // (MT,48): [dt_r | B | C]
            const float* __restrict__ A_log,
            const float* __restrict__ Dp,
            const float* __restrict__ Hstart,
            float* __restrict__ Pbuf, float* __restrict__ hfbuf,
            const short* __restrict__ ycb,    // y-gate (bf16), pass C
            short* __restrict__ poutb)        // pass C out (bf16): p*yc
{
  __shared__ __align__(16) float2 du2_s[16 * 66];             // [ch][t]
  __shared__ __align__(16) float2 BC_s [PASSC ? 16 * 66 : 2]; // [n][t]
  __shared__ __align__(16) float  Bc_s [PASSC ? 4 : 16 * 68]; // [n][t] (pass A)
  __shared__ __align__(16) float  y_s  [PASSC ? 16 * 68 : 4]; // [ch][t]
  const int tid = threadIdx.x;
  const int n = tid & 15, dl = tid >> 4;
  const int ch = blockIdx.x;
  const int d0 = blockIdx.y * 16;
  const int b  = blockIdx.z;
  const int d  = d0 + dl;
  const int t0 = ch * LC;
  const size_t brow = (size_t)b * SEQ;
  // transposed chunk-state index: consecutive tid -> consecutive address
  const size_t cidx = (size_t)ch * NLIN + ((size_t)b * 16 + blockIdx.y) * 256 + tid;

  float u_r[4];
  #pragma unroll
  for (int i = 0; i < 4; i++) {               // cooperative coalesced staging
    int t = (tid >> 4) + i * 16;
    int dd = tid & 15;
    size_t row = brow + t0 + t;
    float uval = bf2f(xcb[row * 256 + d0 + dd]);
    float dval = dtv[row * 256 + d0 + dd];
    du2_s[dd * 66 + t] = make_float2(dval, dval * uval);
    if constexpr (PASSC) {
      BC_s[dd * 66 + t] = make_float2(xdbl[row * 48 + 16 + dd],
                                      xdbl[row * 48 + 32 + dd]);
      u_r[i] = uval;
    } else {
      Bc_s[dd * 68 + t] = xdbl[row * 48 + 16 + dd];
    }
  }
  __syncthreads();

  const float A_dn = -__expf(A_log[d * NST + n]);

  float h = PASSC ? Hstart[cidx] : 0.f;
  float P = 1.f;
  for (int t4 = 0; t4 < LC; t4 += 4) {
    float4 a = *(const float4*)&du2_s[dl * 66 + t4];      // {dt0,du0,dt1,du1}
    float4 c = *(const float4*)&du2_s[dl * 66 + t4 + 2];  // {dt2,du2,dt3,du3}
    float dA[4], du[4];
    dA[0] = __expf(a.x * A_dn); du[0] = a.y;
    dA[1] = __expf(a.z * A_dn); du[1] = a.w;
    dA[2] = __expf(c.x * A_dn); du[2] = c.y;
    dA[3] = __expf(c.z * A_dn); du[3] = c.w;
    if constexpr (!PASSC) {
      float4 f = *(const float4*)&Bc_s[n * 68 + t4];      // B t4..t4+3
      float Bv[4] = {f.x, f.y, f.z, f.w};
      #pragma unroll
      for (int j = 0; j < 4; j++) {
        h = fmaf(dA[j], h, du[j] * Bv[j]);
        P *= dA[j];
      }
    } else {
      float4 e = *(const float4*)&BC_s[n * 66 + t4];      // {B0,C0,B1,C1}
      float4 g = *(const float4*)&BC_s[n * 66 + t4 + 2];  // {B2,C2,B3,C3}
      float Bv[4] = {e.x, e.z, g.x, g.z};
      float Cv[4] = {e.y, e.w, g.y, g.w};
      float yv[4];
      #pragma unroll
      for (int j = 0; j < 4; j++) {
        h = fmaf(dA[j], h, du[j] * Bv[j]);
        yv[j] = h * Cv[j];
      }
      #pragma unroll
      for (int j = 0; j < 4; j++) yv[j] = dpp_add_step<0x118>(yv[j]); // shr8
      #pragma unroll
      for (int j = 0; j < 4; j++) yv[j] = dpp_add_step<0x114>(yv[j]); // shr4
      #pragma unroll
      for (int j = 0; j < 4; j++) yv[j] = dpp_add_step<0x112>(yv[j]); // shr2
      #pragma unroll
      for (int j = 0; j < 4; j++) yv[j] = dpp_add_step<0x111>(yv[j]); // shr1
      if (n == 15)
        *(float4*)&y_s[dl * 68 + t4] = make_float4(yv[0], yv[1], yv[2], yv[3]);
    }
  }

  if constexpr (!PASSC) {
    Pbuf[cidx] = P;                           // coalesced (transposed layout)
    hfbuf[cidx] = h;
  } else {
    __syncthreads();
    const float Dval = Dp[d0 + n];
    #pragma unroll
    for (int i = 0; i < 4; i++) {             // coalesced writeback, fused *yc
      int t = (tid >> 4) + i * 16;
      size_t row = brow + t0 + t;
      float p = fmaf(Dval, u_r[i], y_s[n * 68 + t]);
      float yg = bf2f(ycb[row * 256 + d0 + n]);
      poutb[row * 256 + d0 + n] = f2bf(p * yg);
    }
  }
}

// serial combine across the 64 chunks; one thread per (b,d,n) chain.
// Transposed layout: loads/stores are lane-coalesced each iteration.
__global__ __launch_bounds__(256)
void scan_mid_k(const float* __restrict__ Pbuf, const float* __restrict__ hfbuf,
                float* __restrict__ Hstart)
{
  int lin = blockIdx.x * 256 + threadIdx.x;   // 0..16383
  float H = 0.f;
  for (int c = 0; c < NCHK; c++) {
    size_t idx = (size_t)c * NLIN + lin;
    Hstart[idx] = H;
    H = Pbuf[idx] * H + hfbuf[idx];
  }
}

// ---------------------------------------------------------------------------
extern "C" void kernel_launch(void* const* d_in, const int* in_sizes, int n_in,
                              void* d_out, int out_size, void* d_ws, size_t ws_size,
                              hipStream_t stream)
{
  const float* hs    = (const float*)d_in[0];
  const float* w_in  = (const float*)d_in[1];
  const float* w_xp  = (const float*)d_in[2];
  const float* w_dt  = (const float*)d_in[3];
  const float* b_dt  = (const float*)d_in[4];
  const float* A_log = (const float*)d_in[5];
  const float* Dp    = (const float*)d_in[6];
  const float* w_o1  = (const float*)d_in[7];
  const float* cwx   = (const float*)d_in[8];
  const float* cbx   = (const float*)d_in[9];
  const float* cwy   = (const float*)d_in[10];
  const float* cby   = (const float*)d_in[11];
  const float* cwz   = (const float*)d_in[12];
  const float* cbz   = (const float*)d_in[13];

  char* wsb = (char*)d_ws;
  short* xyzb = (short*)wsb;                            // MT*768 bf16
  short* xcb  = (short*)(wsb + (size_t)MT * 768 * 2);   // MT*256 bf16
  short* ycb  = xcb + (size_t)MT * 256;
  short* zcb  = ycb + (size_t)MT * 256;
  short* pbufb= zcb + (size_t)MT * 256;                 // p*yc (bf16)
  short* w_in_b = pbufb + (size_t)MT * 256;             // 768*256 bf16
  short* w_o1_b = w_in_b + 768 * 256;                   // 256*256 bf16
  short* hsb  = w_o1_b + 256 * 256;                     // MT*256 bf16
  float* xdbl = (float*)(hsb + (size_t)MT * 256 + 128); // MT*48 fp32
  float* dtv  = xdbl + (size_t)MT * 48;                 // MT*256 fp32
  float* Pb   = dtv  + (size_t)MT * 256;                // 1M fp32
  float* hf   = Pb   + (size_t)NCHK * NLIN;
  float* Hs   = hf   + (size_t)NCHK * NLIN;

  dim3 blk(256);

  // K0: weights + hs -> bf16
  cvt_in_k<<<dim3(4352), blk, 0, stream>>>(w_in, w_o1, hs, w_in_b, w_o1_b, hsb);

  // K1: xyz = hs @ in_proj_w^T  (bf16 MFMA, global_load_lds staging)
  mfma_gemm_k<0, true><<<dim3(MT / 128, 768 / 128), blk, 0, stream>>>(
      hsb, w_in_b, xyzb, 768, 256, nullptr, nullptr, nullptr);

  // K2: depthwise conv + SiLU -> xcb, ycb, zcb (bf16), CT=4
  conv_silu_k<<<dim3((MT / CT) * 192 / 256), blk, 0, stream>>>(
      xyzb, cwx, cbx, cwy, cby, cwz, cbz, xcb, ycb, zcb);

  // K3+K4 fused
  gemm34_k<<<dim3(MT / 32), blk, 0, stream>>>(
      xcb, w_xp, w_dt, b_dt, xdbl, dtv);

  // K5-7: chunked selective scan -> pbufb = (scan out)*yc (bf16)
  scan_k<false><<<dim3(NCHK, DM / 16, B_SZ), blk, 0, stream>>>(
      xcb, dtv, xdbl, A_log, Dp, nullptr, Pb, hf, nullptr, nullptr);
  scan_mid_k<<<dim3(NLIN / 256), blk, 0, stream>>>(Pb, hf, Hs);
  scan_k<true><<<dim3(NCHK, DM / 16, B_SZ), blk, 0, stream>>>(
      xcb, dtv, xdbl, A_log, Dp, Hs, nullptr, nullptr, ycb, pbufb);

  // K8: out = (pbufb @ out_proj1_w^T) * zc * cwx + cbx  (fp32 out)
  mfma_gemm_k<2, false><<<dim3(MT / 128, 256 / 128), blk, 0, stream>>>(
      pbufb, w_o1_b, d_out, 256, 256, cbx, zcb, cwx);
}

// Round 17
// 197.660 us; speedup vs baseline: 7.3830x; 1.0192x over previous
//
#include <hip/hip_runtime.h>
#include <hip/hip_bf16.h>
#include <math.h>

typedef __hip_bfloat16 bf16;
typedef __attribute__((ext_vector_type(8))) short bf16x8;
typedef __attribute__((ext_vector_type(4))) float f32x4;

#define B_SZ 4
#define SEQ  4096
#define DM   256
#define NST  16
#define NCHK 64
#define LC   (SEQ/NCHK)      /* 64 */
#define MT   (B_SZ*SEQ)      /* 16384 rows of (b,l) */
#define CT   4               /* l-tile per conv thread */
#define NLIN (B_SZ*16*256)   /* 16384 scan chains */

__device__ __forceinline__ float silu_f(float v){ return v / (1.f + __expf(-v)); }
__device__ __forceinline__ float softplus_f(float v){
  return (v > 15.f) ? v : __logf(1.f + __expf(v));
}
__device__ __forceinline__ short f2bf(float f){
  union { bf16 h; short s; } u; u.h = __float2bfloat16(f); return u.s;
}
__device__ __forceinline__ float bf2f(short s){
  union { unsigned int i; float f; } v;
  v.i = ((unsigned int)(unsigned short)s) << 16; return v.f;
}
__device__ __forceinline__ float4 bf4_to_f4(uint2 q){
  float4 f;
  f.x = bf2f((short)(q.x & 0xffffu)); f.y = bf2f((short)(q.x >> 16));
  f.z = bf2f((short)(q.y & 0xffffu)); f.w = bf2f((short)(q.y >> 16));
  return f;
}
__device__ __forceinline__ short4 f4_to_bf4(float4 f){
  short4 s; s.x = f2bf(f.x); s.y = f2bf(f.y); s.z = f2bf(f.z); s.w = f2bf(f.w);
  return s;
}

// async global->LDS 16B copy (no VGPR round-trip). LDS side must be
// wave-uniform base + lane*16 (m104/m108); global side is per-lane.
__device__ __forceinline__ void async_cp16(const short* g, short* l){
  __builtin_amdgcn_global_load_lds(
      (const __attribute__((address_space(1))) unsigned int*)g,
      (__attribute__((address_space(3))) unsigned int*)l, 16, 0, 0);
}

// DPP row_shr:N add step; after N=8,4,2,1 lane 15 of each row = row sum.
template<int CTRL>
__device__ __forceinline__ float dpp_add_step(float v){
  int x = __builtin_amdgcn_update_dpp(0, __float_as_int(v), CTRL, 0xf, 0xf, true);
  return v + __int_as_float(x);
}

// ---------------------------------------------------------------------------
// Input pre-conversion to bf16: w_in (768x256), w_o1 (256x256), hs (MT x 256).
// ---------------------------------------------------------------------------
__global__ __launch_bounds__(256)
void cvt_in_k(const float* __restrict__ w_in, const float* __restrict__ w_o1,
              const float* __restrict__ hs,
              short* __restrict__ w_in_b, short* __restrict__ w_o1_b,
              short* __restrict__ hsb)
{
  int i = blockIdx.x * 256 + threadIdx.x;     // 0..1114111
  if (i < 49152) {
    float4 q = *(const float4*)&w_in[i * 4];
    *(short4*)&w_in_b[i * 4] = f4_to_bf4(q);
  } else if (i < 65536) {
    int j = i - 49152;
    float4 q = *(const float4*)&w_o1[j * 4];
    *(short4*)&w_o1_b[j * 4] = f4_to_bf4(q);
  } else {
    int j = i - 65536;                        // 0..1048575
    float4 q = *(const float4*)&hs[(size_t)j * 4];
    *(short4*)&hsb[(size_t)j * 4] = f4_to_bf4(q);
  }
}

// ---------------------------------------------------------------------------
// MFMA bf16 GEMM, global_load_lds staging, BM templated (64 or 128), BN=128,
// BK=64. BM=64: 24 KB LDS -> 6 blocks/CU; all 4 waves share A rows (broadcast
// LDS reads), each owns 32 n-cols. XOR-swizzled slots; conflict-free b128
// reads. Grid (m-tiles, n-tiles): m on blockIdx.x (same-m blocks -> same XCD).
// EPI 0: plain store. EPI 2: (acc * zc[m,n] * cwx[n] + bias[n]) (zc bf16).
// ---------------------------------------------------------------------------
template<int EPI, bool OBF, int BM>
__global__ __launch_bounds__(256)
void mfma_gemm_k(const short* __restrict__ Av, const short* __restrict__ Bw,
                 void* __restrict__ Outv, int N, int K,
                 const float* __restrict__ bias, const short* __restrict__ zc,
                 const float* __restrict__ cwx)
{
  constexpr int BN = 128, BK = 64;
  constexpr int JF = (BM == 64) ? 2 : 4;      // j-fragments per wave
  __shared__ short As[BM * BK];
  __shared__ short Bs[BN * BK];
  const int tid  = threadIdx.x;
  const int wave = tid >> 6, lane = tid & 63;
  const int quad = lane >> 4, l16 = lane & 15;
  const int wm = (BM == 64) ? 0 : (wave & 1) * 64;
  const int wn = (BM == 64) ? wave * 32 : (wave >> 1) * 64;
  const int m0 = blockIdx.x * BM, n0 = blockIdx.y * BN;

  f32x4 acc[4][JF] = {};

  for (int k0 = 0; k0 < K; k0 += BK) {
    #pragma unroll
    for (int p = 0; p < BM * 8 / 256; p++) {   // A chunks
      int id = p * 256 + tid;
      int row = id >> 3, slot = id & 7;
      int gch = slot ^ (row & 7);
      async_cp16(Av + (size_t)(m0 + row) * K + k0 + gch * 8,
                 &As[row * 64 + slot * 8]);
    }
    #pragma unroll
    for (int p = 0; p < 4; p++) {              // B chunks (128 rows)
      int id = p * 256 + tid;
      int row = id >> 3, slot = id & 7;
      int gch = slot ^ (row & 7);
      async_cp16(Bw + (size_t)(n0 + row) * K + k0 + gch * 8,
                 &Bs[row * 64 + slot * 8]);
    }
    __syncthreads();                    // drains vmcnt (DMA) for all waves
    #pragma unroll
    for (int ks = 0; ks < 2; ks++) {    // two 32-k steps per BK=64
      bf16x8 fa[4], fb[JF];
      int sa = (ks * 4 + quad) ^ (l16 & 7);
      #pragma unroll
      for (int i = 0; i < 4; i++)
        fa[i] = *(const bf16x8*)&As[(wm + i * 16 + l16) * 64 + sa * 8];
      #pragma unroll
      for (int j = 0; j < JF; j++)
        fb[j] = *(const bf16x8*)&Bs[(wn + j * 16 + l16) * 64 + sa * 8];
      #pragma unroll
      for (int i = 0; i < 4; i++)
        #pragma unroll
        for (int j = 0; j < JF; j++)
          acc[i][j] = __builtin_amdgcn_mfma_f32_16x16x32_bf16(fa[i], fb[j], acc[i][j], 0, 0, 0);
    }
    __syncthreads();
  }

  #pragma unroll
  for (int i = 0; i < 4; i++) {
    #pragma unroll
    for (int j = 0; j < JF; j++) {
      int n = n0 + wn + j * 16 + l16;
      #pragma unroll
      for (int r = 0; r < 4; r++) {
        int m = m0 + wm + i * 16 + quad * 4 + r;
        float v = acc[i][j][r];
        if constexpr (EPI == 2)
          v = v * bf2f(zc[(size_t)m * N + n]) * cwx[n] + bias[n];
        if constexpr (OBF) ((short*)Outv)[(size_t)m * N + n] = f2bf(v);
        else               ((float*)Outv)[(size_t)m * N + n] = v;
      }
    }
  }
}

// ---------------------------------------------------------------------------
// Fused K3+K4 (TM=32): xdbl = xc @ x_proj_w^T; dtv = softplus(dt_r@wdt^T+2b).
// ---------------------------------------------------------------------------
__global__ __launch_bounds__(256)
void gemm34_k(const short* __restrict__ xcb,
              const float* __restrict__ Bw,
              const float* __restrict__ wdt,
              const float* __restrict__ bdt,
              float* __restrict__ xdbl,
              float* __restrict__ dtv)
{
  constexpr int TM = 32, TK = 16, NN = 48;
  __shared__ __align__(16) float As[TK][TM + 4];
  __shared__ __align__(16) float Bs[TK][64 + 4];
  __shared__ __align__(16) float dt_s[TM][20];
  __shared__ __align__(16) float wdt_s[256][20];
  const int tid = threadIdx.x;
  const int tn = tid & 15, tm = tid >> 4;
  const int m0 = blockIdx.x * TM;
  float acc[2][4] = {};
  const int mlA = tid >> 3, kdA = (tid & 7) * 2;
  const int mlB = tid >> 2, kqB = (tid & 3) * 4;

  {
    float4 q0 = *(const float4*)&wdt[tid * 16 + 0];
    float4 q1 = *(const float4*)&wdt[tid * 16 + 4];
    float4 q2 = *(const float4*)&wdt[tid * 16 + 8];
    float4 q3 = *(const float4*)&wdt[tid * 16 + 12];
    *(float4*)&wdt_s[tid][0]  = q0;
    *(float4*)&wdt_s[tid][4]  = q1;
    *(float4*)&wdt_s[tid][8]  = q2;
    *(float4*)&wdt_s[tid][12] = q3;
  }

  for (int k0 = 0; k0 < 256; k0 += TK) {
    {
      size_t off = (size_t)(m0 + mlA) * 256 + k0 + kdA;
      unsigned int v = *(const unsigned int*)(xcb + off);
      As[kdA + 0][mlA] = bf2f((short)(v & 0xffffu));
      As[kdA + 1][mlA] = bf2f((short)(v >> 16));
    }
    {
      float v0 = 0.f, v1 = 0.f, v2 = 0.f, v3 = 0.f;
      if (mlB < NN) {
        float4 q = *(const float4*)(Bw + (size_t)mlB * 256 + k0 + kqB);
        v0 = q.x; v1 = q.y; v2 = q.z; v3 = q.w;
      }
      Bs[kqB+0][mlB] = v0; Bs[kqB+1][mlB] = v1; Bs[kqB+2][mlB] = v2; Bs[kqB+3][mlB] = v3;
    }
    __syncthreads();
    #pragma unroll
    for (int k = 0; k < TK; k++) {
      float2 av = *(const float2*)&As[k][tm << 1];
      float4 bv = *(const float4*)&Bs[k][tn << 2];
      float a[2] = {av.x, av.y};
      float b[4] = {bv.x, bv.y, bv.z, bv.w};
      #pragma unroll
      for (int i = 0; i < 2; i++)
        #pragma unroll
        for (int j = 0; j < 4; j++)
          acc[i][j] = fmaf(a[i], b[j], acc[i][j]);
    }
    __syncthreads();
  }

  #pragma unroll
  for (int i = 0; i < 2; i++) {
    int m = m0 + (tm << 1) + i;
    #pragma unroll
    for (int j = 0; j < 4; j++) {
      int n = (tn << 2) + j;
      float v = acc[i][j];
      if (n < NN) xdbl[(size_t)m * NN + n] = v;
      if (tn < 4) dt_s[(tm << 1) + i][n] = v;
    }
  }
  __syncthreads();

  const int c0 = tid & 63, rg = tid >> 6;
  float w[4][16];
  float bb[4];
  #pragma unroll
  for (int cc = 0; cc < 4; cc++) {
    int col = cc * 64 + c0;
    #pragma unroll
    for (int q = 0; q < 4; q++) {
      float4 t = *(const float4*)&wdt_s[col][q * 4];
      w[cc][q*4+0] = t.x; w[cc][q*4+1] = t.y; w[cc][q*4+2] = t.z; w[cc][q*4+3] = t.w;
    }
    bb[cc] = 2.f * bdt[col];
  }
  #pragma unroll
  for (int rr = 0; rr < 8; rr++) {
    int row = rg * 8 + rr;
    float dr[16];
    #pragma unroll
    for (int q = 0; q < 4; q++) {
      float4 t = *(const float4*)&dt_s[row][q * 4];
      dr[q*4+0] = t.x; dr[q*4+1] = t.y; dr[q*4+2] = t.z; dr[q*4+3] = t.w;
    }
    #pragma unroll
    for (int cc = 0; cc < 4; cc++) {
      float s = bb[cc];
      #pragma unroll
      for (int k = 0; k < 16; k++) s = fmaf(dr[k], w[cc][k], s);
      dtv[(size_t)(m0 + row) * 256 + cc * 64 + c0] = softplus_f(s);
    }
  }
}

// ---------------------------------------------------------------------------
// Depthwise conv + SiLU, register-sliding-window (CT=4), bf16 in/out.
// ---------------------------------------------------------------------------
__global__ __launch_bounds__(256)
void conv_silu_k(const short* __restrict__ xyzb,
                 const float* __restrict__ wx, const float* __restrict__ bx,
                 const float* __restrict__ wy, const float* __restrict__ by,
                 const float* __restrict__ wz, const float* __restrict__ bz,
                 short* __restrict__ xcb, short* __restrict__ ycb,
                 short* __restrict__ zcb)
{
  int idx = blockIdx.x * 256 + threadIdx.x;
  int c4 = idx % 192;
  int lt = idx / 192;
  int row0 = lt * CT;
  int l0 = row0 & (SEQ - 1);

  float4 win[CT + 4];
  #pragma unroll
  for (int i = 0; i < CT + 4; i++) {
    int l = l0 + i - 2;
    if (l >= 0 && l < SEQ)
      win[i] = bf4_to_f4(*(const uint2*)(xyzb + (size_t)(row0 + i - 2) * 768 + c4 * 4));
    else
      win[i] = make_float4(0.f, 0.f, 0.f, 0.f);
  }

  if (c4 < 64) {
    int d = c4 * 4;
    float4 w  = *(const float4*)&wx[d];
    float4 bb = *(const float4*)&bx[d];
    #pragma unroll
    for (int t = 0; t < CT; t++) {
      float4 v = win[t + 2], o;
      o.x = silu_f(fmaf(v.x, w.x, bb.x));
      o.y = silu_f(fmaf(v.y, w.y, bb.y));
      o.z = silu_f(fmaf(v.z, w.z, bb.z));
      o.w = silu_f(fmaf(v.w, w.w, bb.w));
      *(short4*)&xcb[(size_t)(row0 + t) * 256 + d] = f4_to_bf4(o);
    }
  } else if (c4 < 128) {
    int d = (c4 - 64) * 4;
    float wq[4][3];
    #pragma unroll
    for (int q = 0; q < 4; q++)
      #pragma unroll
      for (int j = 0; j < 3; j++) wq[q][j] = wy[(d + q) * 3 + j];
    float4 bb = *(const float4*)&by[d];
    #pragma unroll
    for (int t = 0; t < CT; t++) {
      float a0 = bb.x, a1 = bb.y, a2 = bb.z, a3 = bb.w;
      #pragma unroll
      for (int j = 0; j < 3; j++) {
        float4 v = win[t + 1 + j];
        a0 = fmaf(v.x, wq[0][j], a0);
        a1 = fmaf(v.y, wq[1][j], a1);
        a2 = fmaf(v.z, wq[2][j], a2);
        a3 = fmaf(v.w, wq[3][j], a3);
      }
      float4 o; o.x = silu_f(a0); o.y = silu_f(a1); o.z = silu_f(a2); o.w = silu_f(a3);
      *(short4*)&ycb[(size_t)(row0 + t) * 256 + d] = f4_to_bf4(o);
    }
  } else {
    int d = (c4 - 128) * 4;
    float wq[4][5];
    #pragma unroll
    for (int q = 0; q < 4; q++)
      #pragma unroll
      for (int j = 0; j < 5; j++) wq[q][j] = wz[(d + q) * 5 + j];
    float4 bb = *(const float4*)&bz[d];
    #pragma unroll
    for (int t = 0; t < CT; t++) {
      float a0 = bb.x, a1 = bb.y, a2 = bb.z, a3 = bb.w;
      #pragma unroll
      for (int j = 0; j < 5; j++) {
        float4 v = win[t + j];
        a0 = fmaf(v.x, wq[0][j], a0);
        a1 = fmaf(v.y, wq[1][j], a1);
        a2 = fmaf(v.z, wq[2][j], a2);
        a3 = fmaf(v.w, wq[3][j], a3);
      }
      float4 o; o.x = silu_f(a0); o.y = silu_f(a1); o.z = silu_f(a2); o.w = silu_f(a3);
      *(short4*)&zcb[(size_t)(row0 + t) * 256 + d] = f4_to_bf4(o);
    }
  }
}

// ---------------------------------------------------------------------------
// Chunked selective scan, t-unrolled x4, LDS transposed [channel][t].
// Chunk-state arrays in transposed (coalesced) layout cidx = ch*NLIN + lin.
// Pass C writeback fuses the p*y elementwise product (reads ycb).
// ---------------------------------------------------------------------------
template<bool PASSC>
__global__ __launch_bounds__(256)
void scan_k(const short* __restrict__ xcb,    // u (bf16), (MT,256)
            const float* __restrict__ dtv,    // delta, (MT,256)
            const float* __restrict__ xdbl,   // (MT,48): [dt_r | B | C]
            const float* __restrict__ A_log,
            const float* __restrict__ Dp,
            const float* __restrict__ Hstart,
            float* __restrict__ Pbuf, float* __restrict__ hfbuf,
            const short* __restrict__ ycb,    // y-gate (bf16), pass C
            short* __restrict__ poutb)        // pass C out (bf16): p*yc
{
  __shared__ __align__(16) float2 du2_s[16 * 66];             // [ch][t]
  __shared__ __align__(16) float2 BC_s [PASSC ? 16 * 66 : 2]; // [n][t]
  __shared__ __align__(16) float  Bc_s [PASSC ? 4 : 16 * 68]; // [n][t] (pass A)
  __shared__ __align__(16) float  y_s  [PASSC ? 16 * 68 : 4]; // [ch][t]
  const int tid = threadIdx.x;
  const int n = tid & 15, dl = tid >> 4;
  const int ch = blockIdx.x;
  const int d0 = blockIdx.y * 16;
  const int b  = blockIdx.z;
  const int d  = d0 + dl;
  const int t0 = ch * LC;
  const size_t brow = (size_t)b * SEQ;
  const size_t cidx = (size_t)ch * NLIN + ((size_t)b * 16 + blockIdx.y) * 256 + tid;

  float u_r[4];
  #pragma unroll
  for (int i = 0; i < 4; i++) {               // cooperative coalesced staging
    int t = (tid >> 4) + i * 16;
    int dd = tid & 15;
    size_t row = brow + t0 + t;
    float uval = bf2f(xcb[row * 256 + d0 + dd]);
    float dval = dtv[row * 256 + d0 + dd];
    du2_s[dd * 66 + t] = make_float2(dval, dval * uval);
    if constexpr (PASSC) {
      BC_s[dd * 66 + t] = make_float2(xdbl[row * 48 + 16 + dd],
                                      xdbl[row * 48 + 32 + dd]);
      u_r[i] = uval;
    } else {
      Bc_s[dd * 68 + t] = xdbl[row * 48 + 16 + dd];
    }
  }
  __syncthreads();

  const float A_dn = -__expf(A_log[d * NST + n]);

  float h = PASSC ? Hstart[cidx] : 0.f;
  float P = 1.f;
  for (int t4 = 0; t4 < LC; t4 += 4) {
    float4 a = *(const float4*)&du2_s[dl * 66 + t4];      // {dt0,du0,dt1,du1}
    float4 c = *(const float4*)&du2_s[dl * 66 + t4 + 2];  // {dt2,du2,dt3,du3}
    float dA[4], du[4];
    dA[0] = __expf(a.x * A_dn); du[0] = a.y;
    dA[1] = __expf(a.z * A_dn); du[1] = a.w;
    dA[2] = __expf(c.x * A_dn); du[2] = c.y;
    dA[3] = __expf(c.z * A_dn); du[3] = c.w;
    if constexpr (!PASSC) {
      float4 f = *(const float4*)&Bc_s[n * 68 + t4];      // B t4..t4+3
      float Bv[4] = {f.x, f.y, f.z, f.w};
      #pragma unroll
      for (int j = 0; j < 4; j++) {
        h = fmaf(dA[j], h, du[j] * Bv[j]);
        P *= dA[j];
      }
    } else {
      float4 e = *(const float4*)&BC_s[n * 66 + t4];      // {B0,C0,B1,C1}
      float4 g = *(const float4*)&BC_s[n * 66 + t4 + 2];  // {B2,C2,B3,C3}
      float Bv[4] = {e.x, e.z, g.x, g.z};
      float Cv[4] = {e.y, e.w, g.y, g.w};
      float yv[4];
      #pragma unroll
      for (int j = 0; j < 4; j++) {
        h = fmaf(dA[j], h, du[j] * Bv[j]);
        yv[j] = h * Cv[j];
      }
      #pragma unroll
      for (int j = 0; j < 4; j++) yv[j] = dpp_add_step<0x118>(yv[j]); // shr8
      #pragma unroll
      for (int j = 0; j < 4; j++) yv[j] = dpp_add_step<0x114>(yv[j]); // shr4
      #pragma unroll
      for (int j = 0; j < 4; j++) yv[j] = dpp_add_step<0x112>(yv[j]); // shr2
      #pragma unroll
      for (int j = 0; j < 4; j++) yv[j] = dpp_add_step<0x111>(yv[j]); // shr1
      if (n == 15)
        *(float4*)&y_s[dl * 68 + t4] = make_float4(yv[0], yv[1], yv[2], yv[3]);
    }
  }

  if constexpr (!PASSC) {
    Pbuf[cidx] = P;                           // coalesced (transposed layout)
    hfbuf[cidx] = h;
  } else {
    __syncthreads();
    const float Dval = Dp[d0 + n];
    #pragma unroll
    for (int i = 0; i < 4; i++) {             // coalesced writeback, fused *yc
      int t = (tid >> 4) + i * 16;
      size_t row = brow + t0 + t;
      float p = fmaf(Dval, u_r[i], y_s[n * 68 + t]);
      float yg = bf2f(ycb[row * 256 + d0 + n]);
      poutb[row * 256 + d0 + n] = f2bf(p * yg);
    }
  }
}

// serial combine across the 64 chunks; transposed layout -> coalesced.
__global__ __launch_bounds__(256)
void scan_mid_k(const float* __restrict__ Pbuf, const float* __restrict__ hfbuf,
                float* __restrict__ Hstart)
{
  int lin = blockIdx.x * 256 + threadIdx.x;   // 0..16383
  float H = 0.f;
  for (int c = 0; c < NCHK; c++) {
    size_t idx = (size_t)c * NLIN + lin;
    Hstart[idx] = H;
    H = Pbuf[idx] * H + hfbuf[idx];
  }
}

// ---------------------------------------------------------------------------
extern "C" void kernel_launch(void* const* d_in, const int* in_sizes, int n_in,
                              void* d_out, int out_size, void* d_ws, size_t ws_size,
                              hipStream_t stream)
{
  const float* hs    = (const float*)d_in[0];
  const float* w_in  = (const float*)d_in[1];
  const float* w_xp  = (const float*)d_in[2];
  const float* w_dt  = (const float*)d_in[3];
  const float* b_dt  = (const float*)d_in[4];
  const float* A_log = (const float*)d_in[5];
  const float* Dp    = (const float*)d_in[6];
  const float* w_o1  = (const float*)d_in[7];
  const float* cwx   = (const float*)d_in[8];
  const float* cbx   = (const float*)d_in[9];
  const float* cwy   = (const float*)d_in[10];
  const float* cby   = (const float*)d_in[11];
  const float* cwz   = (const float*)d_in[12];
  const float* cbz   = (const float*)d_in[13];

  char* wsb = (char*)d_ws;
  short* xyzb = (short*)wsb;                            // MT*768 bf16
  short* xcb  = (short*)(wsb + (size_t)MT * 768 * 2);   // MT*256 bf16
  short* ycb  = xcb + (size_t)MT * 256;
  short* zcb  = ycb + (size_t)MT * 256;
  short* pbufb= zcb + (size_t)MT * 256;                 // p*yc (bf16)
  short* w_in_b = pbufb + (size_t)MT * 256;             // 768*256 bf16
  short* w_o1_b = w_in_b + 768 * 256;                   // 256*256 bf16
  short* hsb  = w_o1_b + 256 * 256;                     // MT*256 bf16
  float* xdbl = (float*)(hsb + (size_t)MT * 256 + 128); // MT*48 fp32
  float* dtv  = xdbl + (size_t)MT * 48;                 // MT*256 fp32
  float* Pb   = dtv  + (size_t)MT * 256;                // 1M fp32
  float* hf   = Pb   + (size_t)NCHK * NLIN;
  float* Hs   = hf   + (size_t)NCHK * NLIN;

  dim3 blk(256);

  // K0: weights + hs -> bf16
  cvt_in_k<<<dim3(4352), blk, 0, stream>>>(w_in, w_o1, hs, w_in_b, w_o1_b, hsb);

  // K1: xyz = hs @ in_proj_w^T  (bf16 MFMA, BM=64 -> 1536 blocks, 6/CU)
  mfma_gemm_k<0, true, 64><<<dim3(MT / 64, 768 / 128), blk, 0, stream>>>(
      hsb, w_in_b, xyzb, 768, 256, nullptr, nullptr, nullptr);

  // K2: depthwise conv + SiLU -> xcb, ycb, zcb (bf16), CT=4
  conv_silu_k<<<dim3((MT / CT) * 192 / 256), blk, 0, stream>>>(
      xyzb, cwx, cbx, cwy, cby, cwz, cbz, xcb, ycb, zcb);

  // K3+K4 fused
  gemm34_k<<<dim3(MT / 32), blk, 0, stream>>>(
      xcb, w_xp, w_dt, b_dt, xdbl, dtv);

  // K5-7: chunked selective scan -> pbufb = (scan out)*yc (bf16)
  scan_k<false><<<dim3(NCHK, DM / 16, B_SZ), blk, 0, stream>>>(
      xcb, dtv, xdbl, A_log, Dp, nullptr, Pb, hf, nullptr, nullptr);
  scan_mid_k<<<dim3(NLIN / 256), blk, 0, stream>>>(Pb, hf, Hs);
  scan_k<true><<<dim3(NCHK, DM / 16, B_SZ), blk, 0, stream>>>(
      xcb, dtv, xdbl, A_log, Dp, Hs, nullptr, nullptr, ycb, pbufb);

  // K8: out = (pbufb @ out_proj1_w^T) * zc * cwx + cbx  (BM=64 -> 512 blocks)
  mfma_gemm_k<2, false, 64><<<dim3(MT / 64, 256 / 128), blk, 0, stream>>>(
      pbufb, w_o1_b, d_out, 256, 256, cbx, zcb, cwx);
}